// Round 8
// baseline (158.771 us; speedup 1.0000x reference)
//
#include <hip/hip_runtime.h>

#define DM 1024
#define NH 16
#define DK 64
#define SEQ 2048

typedef __attribute__((ext_vector_type(8))) __bf16 bf16x8;
typedef __attribute__((ext_vector_type(4))) float f32x4;
typedef __attribute__((ext_vector_type(16))) float f32x16;
typedef __attribute__((ext_vector_type(8))) unsigned short u16x8;
typedef __attribute__((ext_vector_type(4))) unsigned int u32x4;
typedef unsigned short u16;

#define MFMA(a, b, c) __builtin_amdgcn_mfma_f32_16x16x32_bf16(a, b, c, 0, 0, 0)
#define MFMA32(a, b, c) __builtin_amdgcn_mfma_f32_32x32x16_bf16(a, b, c, 0, 0, 0)

__device__ __forceinline__ u16 f2bf(float f) {
    unsigned u = __builtin_bit_cast(unsigned, f);
    u = (u + 0x7FFFu + ((u >> 16) & 1u)) >> 16;
    return (u16)u;
}

__device__ __forceinline__ bf16x8 ldb(const u16* p) {
    u16x8 v = *(const u16x8*)p;
    return __builtin_bit_cast(bf16x8, v);
}

__device__ __forceinline__ unsigned cvtpk(float a, float b) {
    unsigned r;
    asm("v_cvt_pk_bf16_f32 %0, %1, %2" : "=v"(r) : "v"(a), "v"(b));
    return r;
}

__device__ __forceinline__ void swap32(unsigned& a, unsigned& b) {
    asm volatile("v_permlane32_swap_b32 %0, %1" : "+v"(a), "+v"(b));
}

// async global->LDS, 16B per lane, LDS dest = wave-uniform base + lane*16
__device__ __forceinline__ void gload16(const u16* g, u16* l) {
    __builtin_amdgcn_global_load_lds(
        (const __attribute__((address_space(1))) unsigned int*)g,
        (__attribute__((address_space(3))) unsigned int*)l, 16, 0, 0);
}

// ---------------- elementwise f32 -> bf16 (vectorized x4) ----------------
__global__ __launch_bounds__(256) void k_cvt_bf16(const float* __restrict__ in,
                                                  u16* __restrict__ out, int n4) {
    int i = blockIdx.x * 256 + threadIdx.x;
    if (i < n4) {
        float4 v = ((const float4*)in)[i];
        ushort4 o;
        o.x = f2bf(v.x); o.y = f2bf(v.y); o.z = f2bf(v.z); o.w = f2bf(v.w);
        ((ushort4*)out)[i] = o;
    }
}

// ------ tiled transpose + convert: W[K][ldW] (cols n0..) f32 -> WT[N][K] bf16 ------
__global__ __launch_bounds__(256) void k_transpose(const float* __restrict__ W,
                                                   u16* __restrict__ WT, int ldW,
                                                   int K, int N) {
    __shared__ float t[32][33];
    int n0 = blockIdx.x * 32, k0 = blockIdx.y * 32;
    int tx = threadIdx.x & 31, ty = threadIdx.x >> 5;
#pragma unroll
    for (int i = 0; i < 32; i += 8)
        t[ty + i][tx] = W[(long)(k0 + ty + i) * ldW + n0 + tx];
    __syncthreads();
#pragma unroll
    for (int i = 0; i < 32; i += 8)
        WT[(long)(n0 + ty + i) * K + k0 + tx] = f2bf(t[tx][ty + i]);
}

// ---- bf16 GEMM (m97 structure): C[M][N] f32 = A[M][K] * BT[N][K]^T ----
__global__ __launch_bounds__(256) void k_gemm128(const u16* __restrict__ A,
                                                 const u16* __restrict__ BT,
                                                 float* __restrict__ C, int N, int K) {
    __shared__ __align__(16) u16 As[128 * 64];
    __shared__ __align__(16) u16 Bs[128 * 64];
    int tid = threadIdx.x;
    int w = tid >> 6, lane = tid & 63, lg = lane >> 4, lr = lane & 15;
    int wr = w >> 1, wc = w & 1;
    int m0 = blockIdx.y * 128, n0 = blockIdx.x * 128;
    int lrow = lane >> 3, lcol = (lane & 7) * 8;
    f32x4 acc[4][4] = {};
    for (int k0 = 0; k0 < K; k0 += 64) {
#pragma unroll
        for (int it = 0; it < 4; ++it) {
            int row = w * 32 + it * 8;
            gload16(A + (long)(m0 + row + lrow) * K + k0 + lcol, &As[row * 64]);
            gload16(BT + (long)(n0 + row + lrow) * K + k0 + lcol, &Bs[row * 64]);
        }
        __syncthreads();
#pragma unroll
        for (int kk = 0; kk < 64; kk += 32) {
            bf16x8 af[4], bf[4];
#pragma unroll
            for (int i = 0; i < 4; ++i) {
                af[i] = ldb(&As[(wr * 64 + i * 16 + lr) * 64 + kk + lg * 8]);
                bf[i] = ldb(&Bs[(wc * 64 + i * 16 + lr) * 64 + kk + lg * 8]);
            }
#pragma unroll
            for (int mi = 0; mi < 4; ++mi)
#pragma unroll
                for (int ni = 0; ni < 4; ++ni)
                    acc[mi][ni] = MFMA(af[mi], bf[ni], acc[mi][ni]);
        }
        __syncthreads();
    }
#pragma unroll
    for (int mi = 0; mi < 4; ++mi)
#pragma unroll
        for (int ni = 0; ni < 4; ++ni)
#pragma unroll
            for (int r = 0; r < 4; ++r) {
                int row = m0 + wr * 64 + mi * 16 + lg * 4 + r;
                int col = n0 + wc * 64 + ni * 16 + lr;
                C[(long)row * N + col] = acc[mi][ni][r];
            }
}

// ---- Q projection GEMM with fused RoPE + bf16 output (N=K=1024 fixed) ----
// epilogue: lane pair (lr, lr^1) holds cols (c, c^1) of the same row; rotate
// via shfl_xor(1), scale by 0.125*log2e, pack pairs to u32 stores.
__global__ __launch_bounds__(256) void k_gemmQ(const u16* __restrict__ A,
                                               const u16* __restrict__ BT,
                                               u16* __restrict__ Qb) {
    const int N = DM, K = DM;
    __shared__ __align__(16) u16 As[128 * 64];
    __shared__ __align__(16) u16 Bs[128 * 64];
    int tid = threadIdx.x;
    int w = tid >> 6, lane = tid & 63, lg = lane >> 4, lr = lane & 15;
    int wr = w >> 1, wc = w & 1;
    int m0 = blockIdx.y * 128, n0 = blockIdx.x * 128;
    int lrow = lane >> 3, lcol = (lane & 7) * 8;
    f32x4 acc[4][4] = {};
    for (int k0 = 0; k0 < K; k0 += 64) {
#pragma unroll
        for (int it = 0; it < 4; ++it) {
            int row = w * 32 + it * 8;
            gload16(A + (long)(m0 + row + lrow) * K + k0 + lcol, &As[row * 64]);
            gload16(BT + (long)(n0 + row + lrow) * K + k0 + lcol, &Bs[row * 64]);
        }
        __syncthreads();
#pragma unroll
        for (int kk = 0; kk < 64; kk += 32) {
            bf16x8 af[4], bf[4];
#pragma unroll
            for (int i = 0; i < 4; ++i) {
                af[i] = ldb(&As[(wr * 64 + i * 16 + lr) * 64 + kk + lg * 8]);
                bf[i] = ldb(&Bs[(wc * 64 + i * 16 + lr) * 64 + kk + lg * 8]);
            }
#pragma unroll
            for (int mi = 0; mi < 4; ++mi)
#pragma unroll
                for (int ni = 0; ni < 4; ++ni)
                    acc[mi][ni] = MFMA(af[mi], bf[ni], acc[mi][ni]);
        }
        __syncthreads();
    }
    const float SC = 0.18033688011112042f;  // 0.125 * log2(e)
#pragma unroll
    for (int ni = 0; ni < 4; ++ni) {
        int col = n0 + wc * 64 + ni * 16 + lr;
        int ii = (col & 63) >> 1;
        float theta = exp2f(-(float)ii * 0.4152410118609203f);  // 10000^(-2i/64)
        float st, ct;
        sincosf(theta, &st, &ct);
#pragma unroll
        for (int mi = 0; mi < 4; ++mi) {
            int row0 = m0 + wr * 64 + mi * 16 + lg * 4;
            int s0 = row0 & (SEQ - 1);
            float sn, cs;
            sincosf((float)s0 * theta, &sn, &cs);
#pragma unroll
            for (int r = 0; r < 4; ++r) {
                float mine = acc[mi][ni][r];
                float other = __shfl_xor(mine, 1);
                float o = ((col & 1) ? (mine * cs + other * sn)
                                     : (mine * cs - other * sn)) * SC;
                float oo = __shfl_xor(o, 1);
                if (!(lr & 1))
                    *(unsigned*)(Qb + (long)(row0 + r) * DM + col) = cvtpk(o, oo);
                float cs2 = cs * ct - sn * st;  // advance angle by theta (next row)
                sn = sn * ct + cs * st;
                cs = cs2;
            }
        }
    }
}

// ---------------- RoPE for K (reads fused KV buffer, row stride 128) ----------------
__global__ __launch_bounds__(256) void k_rope_k(const float* __restrict__ KVf,
                                                u16* __restrict__ Kb) {
    int idx = blockIdx.x * 256 + threadIdx.x;  // B*S*32
    int i = idx & 31;
    int r = idx >> 5;  // b*S + s
    int s = r & (SEQ - 1);
    float theta = exp2f(-(float)i * 0.4152410118609203f);
    float ang = (float)s * theta;
    float sn, cs;
    sincosf(ang, &sn, &cs);
    const float* p = KVf + (long)r * 128 + 2 * i;
    float x1 = p[0], x2 = p[1];
    u16* o = Kb + (long)r * DK + 2 * i;
    o[0] = f2bf(x1 * cs - x2 * sn);
    o[1] = f2bf(x2 * cs + x1 * sn);
}

// ============ attention: 4 waves x 32 q-rows, ring-3 LDS, counted vmcnt ============
// LDS tile = [64 rows][64 bf16] (128B rows). Swizzle: 16B slot ^= (row&7).
// Staging (rule #21): linear LDS dest, inverse-swizzled GLOBAL source per lane.
__device__ __forceinline__ void stage2(u16* dst, const u16* src0, long rstride,
                                       int w, int lane) {
#pragma unroll
    for (int pp = 0; pp < 2; ++pp) {
        int p = w + pp * 4;
        int row = p * 8 + (lane >> 3), slot = lane & 7;
        gload16(src0 + (long)row * rstride + ((slot ^ (row & 7)) * 8), dst + p * 512);
    }
}

// swizzled fragment read: logical (row, 16B-slot) -> 8 bf16
__device__ __forceinline__ bf16x8 lds_frag(const u16* tile, int row, int slot) {
    return ldb(tile + row * 64 + ((slot ^ (row & 7)) * 8));
}

// Swapped QK^T: S^T[kv][q] = mfma(K, Q^T); crow(r,hi) = (r&3) + 8*(r>>2) + 4*hi.
// Swapped PV: O^T[d][q] = mfma(V^T, P^T). log2-domain softmax, deferred max (T13).
template <bool MASKED>
__device__ __forceinline__ void attn_tile(int kv0, int q, int lq, int hi,
                                          const u16* Kt, const u16* Vt,
                                          const bf16x8 qf[4],
                                          f32x16& o0, f32x16& o1,
                                          float& m, float& lsum) {
    f32x16 s0 = {}, s1 = {};
    __builtin_amdgcn_s_setprio(1);
#pragma unroll
    for (int ks = 0; ks < 4; ++ks) {
        s0 = MFMA32(lds_frag(Kt, lq, hi + 2 * ks), qf[ks], s0);
        s1 = MFMA32(lds_frag(Kt, lq + 32, hi + 2 * ks), qf[ks], s1);
    }
    __builtin_amdgcn_s_setprio(0);
    if (MASKED) {
#pragma unroll
        for (int r = 0; r < 16; ++r) {
            int crow = (r & 3) + 8 * (r >> 2) + 4 * hi;
            if (kv0 + crow > q) s0[r] = -3e38f;
            if (kv0 + 32 + crow > q) s1[r] = -3e38f;
        }
    }
    // tree max
    float t[8];
#pragma unroll
    for (int j = 0; j < 8; ++j)
        t[j] = fmaxf(fmaxf(s0[j], s0[j + 8]), fmaxf(s1[j], s1[j + 8]));
    float pmax = fmaxf(fmaxf(fmaxf(t[0], t[4]), fmaxf(t[1], t[5])),
                       fmaxf(fmaxf(t[2], t[6]), fmaxf(t[3], t[7])));
    pmax = fmaxf(pmax, __shfl_xor(pmax, 32));
    if (__any(pmax > m + 8.f)) {
        float mnew = fmaxf(m, pmax);
        float fac = exp2f(m - mnew);
        m = mnew;
        lsum *= fac;
        o0 *= fac;
        o1 *= fac;
    }
    float p0[16], p1[16];
#pragma unroll
    for (int r = 0; r < 16; ++r) {
        p0[r] = exp2f(s0[r] - m);
        p1[r] = exp2f(s1[r] - m);
    }
    // tree sum
    float su[8];
#pragma unroll
    for (int j = 0; j < 8; ++j)
        su[j] = (p0[j] + p0[j + 8]) + (p1[j] + p1[j + 8]);
    float psum = ((su[0] + su[4]) + (su[1] + su[5])) + ((su[2] + su[6]) + (su[3] + su[7]));
    psum += __shfl_xor(psum, 32);
    lsum += psum;
    // pack P into PV B-operand fragments (T12: cvt_pk + permlane32_swap)
    bf16x8 pa[4];
#pragma unroll
    for (int g = 0; g < 2; ++g) {
        unsigned a0 = cvtpk(p0[g * 8 + 0], p0[g * 8 + 1]);
        unsigned b0 = cvtpk(p0[g * 8 + 4], p0[g * 8 + 5]);
        swap32(a0, b0);
        unsigned a1 = cvtpk(p0[g * 8 + 2], p0[g * 8 + 3]);
        unsigned b1 = cvtpk(p0[g * 8 + 6], p0[g * 8 + 7]);
        swap32(a1, b1);
        u32x4 u = {a0, a1, b0, b1};
        pa[g] = __builtin_bit_cast(bf16x8, u);
    }
#pragma unroll
    for (int g = 0; g < 2; ++g) {
        unsigned a0 = cvtpk(p1[g * 8 + 0], p1[g * 8 + 1]);
        unsigned b0 = cvtpk(p1[g * 8 + 4], p1[g * 8 + 5]);
        swap32(a0, b0);
        unsigned a1 = cvtpk(p1[g * 8 + 2], p1[g * 8 + 3]);
        unsigned b1 = cvtpk(p1[g * 8 + 6], p1[g * 8 + 7]);
        swap32(a1, b1);
        u32x4 u = {a0, a1, b0, b1};
        pa[2 + g] = __builtin_bit_cast(bf16x8, u);
    }
    __builtin_amdgcn_s_setprio(1);
#pragma unroll
    for (int ks = 0; ks < 4; ++ks) {
        o0 = MFMA32(lds_frag(Vt, lq, hi + 2 * ks), pa[ks], o0);
        o1 = MFMA32(lds_frag(Vt, lq + 32, hi + 2 * ks), pa[ks], o1);
    }
    __builtin_amdgcn_s_setprio(0);
}

// grid: flat 512 blocks (256 thr = 4 waves, 128 q-rows). Ring-3 double-barrier
// pipeline with counted vmcnt: loads for tiles t+1,t+2 stay in flight across
// barriers (T3/T4); per wave exactly 4 gload16 per tile -> vmcnt(8)/(4)/(0).
__global__ __launch_bounds__(256) void k_attn(const u16* __restrict__ Qb,
                                              const u16* __restrict__ Kb,
                                              const u16* __restrict__ VbT,
                                              u16* __restrict__ Ob) {
    __shared__ __align__(16) u16 lds[3][2][4096];  // [ring][K/V][64x64 bf16] = 48KB
    int id = blockIdx.x;
    int h = id & 15, b = (id >> 4) & 1;
    int qslot = id >> 5;                               // 0..15
    int qt = qslot < 8 ? qslot * 2 : 31 - qslot * 2;   // pair-balanced bijection
    int qb0 = qt * 128;
    int w = threadIdx.x >> 6, lane = threadIdx.x & 63;
    int lq = lane & 31, hi = lane >> 5;
    int q0w = qb0 + 32 * w;
    int q = q0w + lq;
    const u16* Qp = Qb + (long)(b * SEQ + q) * DM + h * DK + hi * 8;
    bf16x8 qf[4];
#pragma unroll
    for (int ks = 0; ks < 4; ++ks) qf[ks] = ldb(Qp + ks * 16);
    const u16* Kbase = Kb + (long)b * SEQ * DK;
    const u16* Vbase = VbT + (long)b * DK * SEQ;
    f32x16 o0 = {}, o1 = {};
    float m = -1e30f, lsum = 0.f;

    int nt = (qb0 >> 6) + 2;  // 64-kv tiles covering [0, qb0+128); nt >= 2
    stage2(&lds[0][0][0], Kbase, DK, w, lane);
    stage2(&lds[0][1][0], Vbase, SEQ, w, lane);
    stage2(&lds[1][0][0], Kbase + (long)64 * DK, DK, w, lane);
    stage2(&lds[1][1][0], Vbase + 64, SEQ, w, lane);
    for (int t = 0; t < nt; ++t) {
        int kv0 = t * 64;
        if (t + 2 < nt) {
            int bi2 = (t + 2) % 3;
            stage2(&lds[bi2][0][0], Kbase + (long)(kv0 + 128) * DK, DK, w, lane);
            stage2(&lds[bi2][1][0], Vbase + kv0 + 128, SEQ, w, lane);
            asm volatile("s_waitcnt vmcnt(8)" ::: "memory");  // tile t landed (mine)
        } else if (t + 1 < nt) {
            asm volatile("s_waitcnt vmcnt(4)" ::: "memory");
        } else {
            asm volatile("s_waitcnt vmcnt(0)" ::: "memory");
        }
        __builtin_amdgcn_s_barrier();  // tile t landed (all waves)
        int bi = t % 3;
        if (kv0 <= q0w + 31) {
            if (kv0 + 63 <= q0w)
                attn_tile<false>(kv0, q, lq, hi, &lds[bi][0][0], &lds[bi][1][0],
                                 qf, o0, o1, m, lsum);
            else
                attn_tile<true>(kv0, q, lq, hi, &lds[bi][0][0], &lds[bi][1][0],
                                qf, o0, o1, m, lsum);
        }
        __builtin_amdgcn_s_barrier();  // all done reading buf[t%3] before overwrite
    }

    float linv = 1.f / lsum;
    // O^T regs -> LDS transpose (reuse ring buffer; last barrier guarantees done)
    u16* Ot = &lds[0][0][0] + w * 2304;  // 32 x 72 u16 per wave
#pragma unroll
    for (int rq = 0; rq < 4; ++rq) {
        uint2 u0, u1;
        u0.x = cvtpk(o0[4 * rq + 0] * linv, o0[4 * rq + 1] * linv);
        u0.y = cvtpk(o0[4 * rq + 2] * linv, o0[4 * rq + 3] * linv);
        u1.x = cvtpk(o1[4 * rq + 0] * linv, o1[4 * rq + 1] * linv);
        u1.y = cvtpk(o1[4 * rq + 2] * linv, o1[4 * rq + 3] * linv);
        *(uint2*)&Ot[lq * 72 + rq * 8 + hi * 4] = u0;
        *(uint2*)&Ot[lq * 72 + 32 + rq * 8 + hi * 4] = u1;
    }
#pragma unroll
    for (int i2 = 0; i2 < 4; ++i2) {
        int c = i2 * 64 + lane;
        int row = c >> 3, col = (c & 7) * 8;
        u16x8 v = *(const u16x8*)&Ot[row * 72 + col];
        *(u16x8*)(Ob + (long)(b * SEQ + q0w + row) * DM + h * DK + col) = v;
    }
}

extern "C" void kernel_launch(void* const* d_in, const int* in_sizes, int n_in,
                              void* d_out, int out_size, void* d_ws, size_t ws_size,
                              hipStream_t stream) {
    const float* x = (const float*)d_in[0];
    const float* Wq = (const float*)d_in[1];
    const float* Wk = (const float*)d_in[2];
    const float* Wv = (const float*)d_in[3];
    const float* Wo = (const float*)d_in[4];
    float* out = (float*)d_out;

    const int M = 2 * SEQ;  // 4096 rows
    char* p = (char*)d_ws;
    u16* xb = (u16*)p;      p += (size_t)M * DM * 2;          // 8 MB
    u16* WqbT = (u16*)p;    p += (size_t)DM * DM * 2;         // 2 MB
    u16* WkvT = (u16*)p;    p += (size_t)2 * DK * DM * 2;     // 256 KB (K rows then V rows)
    u16* WobT = (u16*)p;    p += (size_t)DM * DM * 2;         // 2 MB
    float* KVf = (float*)p; p += (size_t)M * 128 * 4;         // 2 MB (cols 0-63 K, 64-127 V)
    u16* Qb = (u16*)p;      p += (size_t)M * DM * 2;          // 8 MB
    u16* Kb = (u16*)p;      p += (size_t)M * DK * 2;          // 512 KB
    u16* VbT = (u16*)p;     p += (size_t)M * DK * 2;          // 512 KB
    u16* Ob = (u16*)p;      p += (size_t)M * DM * 2;          // 8 MB

    // 1) convert inputs to bf16 (+ weight transposes)
    k_cvt_bf16<<<(M * DM / 4 + 255) / 256, 256, 0, stream>>>(x, xb, M * DM / 4);
    k_transpose<<<dim3(DM / 32, DM / 32), 256, 0, stream>>>(Wq, WqbT, DM, DM, DM);
    k_transpose<<<dim3(DK / 32, DM / 32), 256, 0, stream>>>(Wk, WkvT, DK, DM, DK);
    k_transpose<<<dim3(DK / 32, DM / 32), 256, 0, stream>>>(Wv, WkvT + (size_t)DK * DM, DK, DM, DK);
    k_transpose<<<dim3(DM / 32, DM / 32), 256, 0, stream>>>(Wo, WobT, DM, DM, DM);

    // 2) projections: Q with fused RoPE -> bf16 Qb; K,V fused as N=128 -> f32
    k_gemmQ<<<dim3(DM / 128, M / 128), 256, 0, stream>>>(xb, WqbT, Qb);
    k_gemm128<<<dim3(1, M / 128), 256, 0, stream>>>(xb, WkvT, KVf, 128, DM);

    // 3) RoPE-K + V transpose (to bf16)
    k_rope_k<<<(M * 32) / 256, 256, 0, stream>>>(KVf, Kb);
    for (int bb = 0; bb < 2; ++bb)
        k_transpose<<<dim3(DK / 32, SEQ / 32), 256, 0, stream>>>(
            KVf + (size_t)bb * SEQ * 128 + DK, VbT + (size_t)bb * DK * SEQ, 128, SEQ, DK);

    // 4) attention (ring-3 counted-vmcnt pipeline, pair-balanced grid)
    k_attn<<<dim3(2 * NH * (SEQ / 128)), 256, 0, stream>>>(Qb, Kb, VbT, Ob);

    // 5) output projection -> d_out
    k_gemm128<<<dim3(DM / 128, M / 128), 256, 0, stream>>>(Ob, WobT, out, DM, DM);
}

// Round 10
// 155.378 us; speedup vs baseline: 1.0218x; 1.0218x over previous
//
#include <hip/hip_runtime.h>

#define DM 1024
#define NH 16
#define DK 64
#define SEQ 2048

typedef __attribute__((ext_vector_type(8))) __bf16 bf16x8;
typedef __attribute__((ext_vector_type(4))) float f32x4;
typedef __attribute__((ext_vector_type(16))) float f32x16;
typedef __attribute__((ext_vector_type(8))) unsigned short u16x8;
typedef __attribute__((ext_vector_type(4))) unsigned int u32x4;
typedef unsigned short u16;

#define MFMA(a, b, c) __builtin_amdgcn_mfma_f32_16x16x32_bf16(a, b, c, 0, 0, 0)
#define MFMA32(a, b, c) __builtin_amdgcn_mfma_f32_32x32x16_bf16(a, b, c, 0, 0, 0)

__device__ __forceinline__ u16 f2bf(float f) {
    unsigned u = __builtin_bit_cast(unsigned, f);
    u = (u + 0x7FFFu + ((u >> 16) & 1u)) >> 16;
    return (u16)u;
}

__device__ __forceinline__ bf16x8 ldb(const u16* p) {
    u16x8 v = *(const u16x8*)p;
    return __builtin_bit_cast(bf16x8, v);
}

__device__ __forceinline__ unsigned cvtpk(float a, float b) {
    unsigned r;
    asm("v_cvt_pk_bf16_f32 %0, %1, %2" : "=v"(r) : "v"(a), "v"(b));
    return r;
}

__device__ __forceinline__ void swap32(unsigned& a, unsigned& b) {
    asm volatile("v_permlane32_swap_b32 %0, %1" : "+v"(a), "+v"(b));
}

// fast 2^x: raw v_exp_f32 (we are already in log2 domain)
__device__ __forceinline__ float fexp2(float x) {
    return __builtin_amdgcn_exp2f(x);
}

// async global->LDS, 16B per lane, LDS dest = wave-uniform base + lane*16
__device__ __forceinline__ void gload16(const u16* g, u16* l) {
    __builtin_amdgcn_global_load_lds(
        (const __attribute__((address_space(1))) unsigned int*)g,
        (__attribute__((address_space(3))) unsigned int*)l, 16, 0, 0);
}

// ---------------- elementwise f32 -> bf16 (vectorized x4) ----------------
__global__ __launch_bounds__(256) void k_cvt_bf16(const float* __restrict__ in,
                                                  u16* __restrict__ out, int n4) {
    int i = blockIdx.x * 256 + threadIdx.x;
    if (i < n4) {
        float4 v = ((const float4*)in)[i];
        ushort4 o;
        o.x = f2bf(v.x); o.y = f2bf(v.y); o.z = f2bf(v.z); o.w = f2bf(v.w);
        ((ushort4*)out)[i] = o;
    }
}

// ---------------- RoPE sincos table: tab[s][i] = {cos, sin}(s * theta_i) ----------------
__global__ __launch_bounds__(256) void k_trig(float2* __restrict__ tab) {
    int idx = blockIdx.x * 256 + threadIdx.x;  // SEQ*32
    int i = idx & 31, s = idx >> 5;
    float theta = exp2f(-(float)i * 0.4152410118609203f);  // 10000^(-2i/64)
    float sn, cs;
    sincosf((float)s * theta, &sn, &cs);
    tab[idx] = make_float2(cs, sn);
}

// ------ tiled transpose + convert: W[K][ldW] (cols n0..) f32 -> WT[N][K] bf16 ------
__global__ __launch_bounds__(256) void k_transpose(const float* __restrict__ W,
                                                   u16* __restrict__ WT, int ldW,
                                                   int K, int N) {
    __shared__ float t[32][33];
    int n0 = blockIdx.x * 32, k0 = blockIdx.y * 32;
    int tx = threadIdx.x & 31, ty = threadIdx.x >> 5;
#pragma unroll
    for (int i = 0; i < 32; i += 8)
        t[ty + i][tx] = W[(long)(k0 + ty + i) * ldW + n0 + tx];
    __syncthreads();
#pragma unroll
    for (int i = 0; i < 32; i += 8)
        WT[(long)(n0 + ty + i) * K + k0 + tx] = f2bf(t[tx][ty + i]);
}

// ---- bf16 GEMM (m97 structure): C[M][N] f32 = A[M][K] * BT[N][K]^T ----
__global__ __launch_bounds__(256) void k_gemm128(const u16* __restrict__ A,
                                                 const u16* __restrict__ BT,
                                                 float* __restrict__ C, int N, int K) {
    __shared__ __align__(16) u16 As[128 * 64];
    __shared__ __align__(16) u16 Bs[128 * 64];
    int tid = threadIdx.x;
    int w = tid >> 6, lane = tid & 63, lg = lane >> 4, lr = lane & 15;
    int wr = w >> 1, wc = w & 1;
    int m0 = blockIdx.y * 128, n0 = blockIdx.x * 128;
    int lrow = lane >> 3, lcol = (lane & 7) * 8;
    f32x4 acc[4][4] = {};
    for (int k0 = 0; k0 < K; k0 += 64) {
#pragma unroll
        for (int it = 0; it < 4; ++it) {
            int row = w * 32 + it * 8;
            gload16(A + (long)(m0 + row + lrow) * K + k0 + lcol, &As[row * 64]);
            gload16(BT + (long)(n0 + row + lrow) * K + k0 + lcol, &Bs[row * 64]);
        }
        __syncthreads();
#pragma unroll
        for (int kk = 0; kk < 64; kk += 32) {
            bf16x8 af[4], bf[4];
#pragma unroll
            for (int i = 0; i < 4; ++i) {
                af[i] = ldb(&As[(wr * 64 + i * 16 + lr) * 64 + kk + lg * 8]);
                bf[i] = ldb(&Bs[(wc * 64 + i * 16 + lr) * 64 + kk + lg * 8]);
            }
#pragma unroll
            for (int mi = 0; mi < 4; ++mi)
#pragma unroll
                for (int ni = 0; ni < 4; ++ni)
                    acc[mi][ni] = MFMA(af[mi], bf[ni], acc[mi][ni]);
        }
        __syncthreads();
    }
#pragma unroll
    for (int mi = 0; mi < 4; ++mi)
#pragma unroll
        for (int ni = 0; ni < 4; ++ni)
#pragma unroll
            for (int r = 0; r < 4; ++r) {
                int row = m0 + wr * 64 + mi * 16 + lg * 4 + r;
                int col = n0 + wc * 64 + ni * 16 + lr;
                C[(long)row * N + col] = acc[mi][ni][r];
            }
}

// ---- Q projection GEMM with fused RoPE (table-driven) + bf16 output ----
__global__ __launch_bounds__(256) void k_gemmQ(const u16* __restrict__ A,
                                               const u16* __restrict__ BT,
                                               const float2* __restrict__ tab,
                                               u16* __restrict__ Qb) {
    const int K = DM;
    __shared__ __align__(16) u16 As[128 * 64];
    __shared__ __align__(16) u16 Bs[128 * 64];
    int tid = threadIdx.x;
    int w = tid >> 6, lane = tid & 63, lg = lane >> 4, lr = lane & 15;
    int wr = w >> 1, wc = w & 1;
    int m0 = blockIdx.y * 128, n0 = blockIdx.x * 128;
    int lrow = lane >> 3, lcol = (lane & 7) * 8;
    f32x4 acc[4][4] = {};
    for (int k0 = 0; k0 < K; k0 += 64) {
#pragma unroll
        for (int it = 0; it < 4; ++it) {
            int row = w * 32 + it * 8;
            gload16(A + (long)(m0 + row + lrow) * K + k0 + lcol, &As[row * 64]);
            gload16(BT + (long)(n0 + row + lrow) * K + k0 + lcol, &Bs[row * 64]);
        }
        __syncthreads();
#pragma unroll
        for (int kk = 0; kk < 64; kk += 32) {
            bf16x8 af[4], bf[4];
#pragma unroll
            for (int i = 0; i < 4; ++i) {
                af[i] = ldb(&As[(wr * 64 + i * 16 + lr) * 64 + kk + lg * 8]);
                bf[i] = ldb(&Bs[(wc * 64 + i * 16 + lr) * 64 + kk + lg * 8]);
            }
#pragma unroll
            for (int mi = 0; mi < 4; ++mi)
#pragma unroll
                for (int ni = 0; ni < 4; ++ni)
                    acc[mi][ni] = MFMA(af[mi], bf[ni], acc[mi][ni]);
        }
        __syncthreads();
    }
    const float SC = 0.18033688011112042f;  // 0.125 * log2(e)
#pragma unroll
    for (int ni = 0; ni < 4; ++ni) {
        int col = n0 + wc * 64 + ni * 16 + lr;
        int ii = (col & 63) >> 1;
#pragma unroll
        for (int mi = 0; mi < 4; ++mi) {
            int row0 = m0 + wr * 64 + mi * 16 + lg * 4;
#pragma unroll
            for (int r = 0; r < 4; ++r) {
                int s = (row0 + r) & (SEQ - 1);
                float2 t = tab[s * 32 + ii];
                float mine = acc[mi][ni][r];
                float other = __shfl_xor(mine, 1);
                float o = ((col & 1) ? (mine * t.x + other * t.y)
                                     : (mine * t.x - other * t.y)) * SC;
                float oo = __shfl_xor(o, 1);
                if (!(lr & 1))
                    *(unsigned*)(Qb + (long)(row0 + r) * DM + col) = cvtpk(o, oo);
            }
        }
    }
}

// ---------------- RoPE for K (table-driven; reads fused KV buffer, stride 128) ----------------
__global__ __launch_bounds__(256) void k_rope_k(const float* __restrict__ KVf,
                                                const float2* __restrict__ tab,
                                                u16* __restrict__ Kb) {
    int idx = blockIdx.x * 256 + threadIdx.x;  // B*S*32
    int i = idx & 31;
    int r = idx >> 5;  // b*S + s
    int s = r & (SEQ - 1);
    float2 t = tab[s * 32 + i];
    const float* p = KVf + (long)r * 128 + 2 * i;
    float x1 = p[0], x2 = p[1];
    u16* o = Kb + (long)r * DK + 2 * i;
    o[0] = f2bf(x1 * t.x - x2 * t.y);
    o[1] = f2bf(x2 * t.x + x1 * t.y);
}

// ============ attention: 4 waves x 32 q-rows, ring-3 LDS, counted vmcnt ============
// LDS tile = [64 rows][64 bf16] (128B rows). Swizzle: 16B slot ^= (row&7).
// Staging (rule #21): linear LDS dest, inverse-swizzled GLOBAL source per lane.
__device__ __forceinline__ void stage2(u16* dst, const u16* src0, long rstride,
                                       int w, int lane) {
#pragma unroll
    for (int pp = 0; pp < 2; ++pp) {
        int p = w + pp * 4;
        int row = p * 8 + (lane >> 3), slot = lane & 7;
        gload16(src0 + (long)row * rstride + ((slot ^ (row & 7)) * 8), dst + p * 512);
    }
}

// swizzled fragment read: logical (row, 16B-slot) -> 8 bf16
__device__ __forceinline__ bf16x8 lds_frag(const u16* tile, int row, int slot) {
    return ldb(tile + row * 64 + ((slot ^ (row & 7)) * 8));
}

// Swapped QK^T: S^T[kv][q] = mfma(K, Q^T); crow(r,hi) = (r&3) + 8*(r>>2) + 4*hi.
// Swapped PV: O^T[d][q] = mfma(V^T, P^T). log2-domain softmax, deferred max (T13).
template <bool MASKED>
__device__ __forceinline__ void attn_tile(int kv0, int q, int lq, int hi,
                                          const u16* Kt, const u16* Vt,
                                          const bf16x8 qf[4],
                                          f32x16& o0, f32x16& o1,
                                          float& m, float& lsum) {
    f32x16 s0 = {}, s1 = {};
    __builtin_amdgcn_s_setprio(1);
#pragma unroll
    for (int ks = 0; ks < 4; ++ks) {
        s0 = MFMA32(lds_frag(Kt, lq, hi + 2 * ks), qf[ks], s0);
        s1 = MFMA32(lds_frag(Kt, lq + 32, hi + 2 * ks), qf[ks], s1);
    }
    __builtin_amdgcn_s_setprio(0);
    if (MASKED) {
#pragma unroll
        for (int r = 0; r < 16; ++r) {
            int crow = (r & 3) + 8 * (r >> 2) + 4 * hi;
            if (kv0 + crow > q) s0[r] = -3e38f;
            if (kv0 + 32 + crow > q) s1[r] = -3e38f;
        }
    }
    // tree max
    float t[8];
#pragma unroll
    for (int j = 0; j < 8; ++j)
        t[j] = fmaxf(fmaxf(s0[j], s0[j + 8]), fmaxf(s1[j], s1[j + 8]));
    float pmax = fmaxf(fmaxf(fmaxf(t[0], t[4]), fmaxf(t[1], t[5])),
                       fmaxf(fmaxf(t[2], t[6]), fmaxf(t[3], t[7])));
    pmax = fmaxf(pmax, __shfl_xor(pmax, 32));
    if (__any(pmax > m + 8.f)) {
        float mnew = fmaxf(m, pmax);
        float fac = fexp2(m - mnew);
        m = mnew;
        lsum *= fac;
        o0 *= fac;
        o1 *= fac;
    }
    float p0[16], p1[16];
#pragma unroll
    for (int r = 0; r < 16; ++r) {
        p0[r] = fexp2(s0[r] - m);
        p1[r] = fexp2(s1[r] - m);
    }
    // tree sum
    float su[8];
#pragma unroll
    for (int j = 0; j < 8; ++j)
        su[j] = (p0[j] + p0[j + 8]) + (p1[j] + p1[j + 8]);
    float psum = ((su[0] + su[4]) + (su[1] + su[5])) + ((su[2] + su[6]) + (su[3] + su[7]));
    psum += __shfl_xor(psum, 32);
    lsum += psum;
    // pack P into PV B-operand fragments (T12: cvt_pk + permlane32_swap)
    bf16x8 pa[4];
#pragma unroll
    for (int g = 0; g < 2; ++g) {
        unsigned a0 = cvtpk(p0[g * 8 + 0], p0[g * 8 + 1]);
        unsigned b0 = cvtpk(p0[g * 8 + 4], p0[g * 8 + 5]);
        swap32(a0, b0);
        unsigned a1 = cvtpk(p0[g * 8 + 2], p0[g * 8 + 3]);
        unsigned b1 = cvtpk(p0[g * 8 + 6], p0[g * 8 + 7]);
        swap32(a1, b1);
        u32x4 u = {a0, a1, b0, b1};
        pa[g] = __builtin_bit_cast(bf16x8, u);
    }
#pragma unroll
    for (int g = 0; g < 2; ++g) {
        unsigned a0 = cvtpk(p1[g * 8 + 0], p1[g * 8 + 1]);
        unsigned b0 = cvtpk(p1[g * 8 + 4], p1[g * 8 + 5]);
        swap32(a0, b0);
        unsigned a1 = cvtpk(p1[g * 8 + 2], p1[g * 8 + 3]);
        unsigned b1 = cvtpk(p1[g * 8 + 6], p1[g * 8 + 7]);
        swap32(a1, b1);
        u32x4 u = {a0, a1, b0, b1};
        pa[2 + g] = __builtin_bit_cast(bf16x8, u);
    }
    __builtin_amdgcn_s_setprio(1);
#pragma unroll
    for (int ks = 0; ks < 4; ++ks) {
        o0 = MFMA32(lds_frag(Vt, lq, hi + 2 * ks), pa[ks], o0);
        o1 = MFMA32(lds_frag(Vt, lq + 32, hi + 2 * ks), pa[ks], o1);
    }
    __builtin_amdgcn_s_setprio(0);
}

// grid: flat 512 blocks (256 thr = 4 waves, 128 q-rows). Ring-3 double-barrier
// pipeline with counted vmcnt: loads for tiles t+1,t+2 stay in flight across
// barriers (T3/T4); per wave exactly 4 gload16 per tile -> vmcnt(8)/(4)/(0).
__global__ __launch_bounds__(256) void k_attn(const u16* __restrict__ Qb,
                                              const u16* __restrict__ Kb,
                                              const u16* __restrict__ VbT,
                                              u16* __restrict__ Ob) {
    __shared__ __align__(16) u16 lds[3][2][4096];  // [ring][K/V][64x64 bf16] = 48KB
    int id = blockIdx.x;
    int h = id & 15, b = (id >> 4) & 1;
    int qslot = id >> 5;                               // 0..15
    int qt = qslot < 8 ? qslot * 2 : 31 - qslot * 2;   // pair-balanced bijection
    int qb0 = qt * 128;
    int w = threadIdx.x >> 6, lane = threadIdx.x & 63;
    int lq = lane & 31, hi = lane >> 5;
    int q0w = qb0 + 32 * w;
    int q = q0w + lq;
    const u16* Qp = Qb + (long)(b * SEQ + q) * DM + h * DK + hi * 8;
    bf16x8 qf[4];
#pragma unroll
    for (int ks = 0; ks < 4; ++ks) qf[ks] = ldb(Qp + ks * 16);
    const u16* Kbase = Kb + (long)b * SEQ * DK;
    const u16* Vbase = VbT + (long)b * DK * SEQ;
    f32x16 o0 = {}, o1 = {};
    float m = -1e30f, lsum = 0.f;

    int nt = (qb0 >> 6) + 2;  // 64-kv tiles covering [0, qb0+128); nt >= 2
    stage2(&lds[0][0][0], Kbase, DK, w, lane);
    stage2(&lds[0][1][0], Vbase, SEQ, w, lane);
    stage2(&lds[1][0][0], Kbase + (long)64 * DK, DK, w, lane);
    stage2(&lds[1][1][0], Vbase + 64, SEQ, w, lane);
    for (int t = 0; t < nt; ++t) {
        int kv0 = t * 64;
        if (t + 2 < nt) {
            int bi2 = (t + 2) % 3;
            stage2(&lds[bi2][0][0], Kbase + (long)(kv0 + 128) * DK, DK, w, lane);
            stage2(&lds[bi2][1][0], Vbase + kv0 + 128, SEQ, w, lane);
            asm volatile("s_waitcnt vmcnt(8)" ::: "memory");  // tile t landed (mine)
        } else if (t + 1 < nt) {
            asm volatile("s_waitcnt vmcnt(4)" ::: "memory");
        } else {
            asm volatile("s_waitcnt vmcnt(0)" ::: "memory");
        }
        __builtin_amdgcn_s_barrier();  // tile t landed (all waves)
        int bi = t % 3;
        if (kv0 <= q0w + 31) {
            if (kv0 + 63 <= q0w)
                attn_tile<false>(kv0, q, lq, hi, &lds[bi][0][0], &lds[bi][1][0],
                                 qf, o0, o1, m, lsum);
            else
                attn_tile<true>(kv0, q, lq, hi, &lds[bi][0][0], &lds[bi][1][0],
                                qf, o0, o1, m, lsum);
        }
        __builtin_amdgcn_s_barrier();  // all done reading buf[t%3] before overwrite
    }

    float linv = 1.f / lsum;
    // O^T regs -> LDS transpose (reuse ring buffer; last barrier guarantees done)
    u16* Ot = &lds[0][0][0] + w * 2304;  // 32 x 72 u16 per wave
#pragma unroll
    for (int rq = 0; rq < 4; ++rq) {
        uint2 u0, u1;
        u0.x = cvtpk(o0[4 * rq + 0] * linv, o0[4 * rq + 1] * linv);
        u0.y = cvtpk(o0[4 * rq + 2] * linv, o0[4 * rq + 3] * linv);
        u1.x = cvtpk(o1[4 * rq + 0] * linv, o1[4 * rq + 1] * linv);
        u1.y = cvtpk(o1[4 * rq + 2] * linv, o1[4 * rq + 3] * linv);
        *(uint2*)&Ot[lq * 72 + rq * 8 + hi * 4] = u0;
        *(uint2*)&Ot[lq * 72 + 32 + rq * 8 + hi * 4] = u1;
    }
#pragma unroll
    for (int i2 = 0; i2 < 4; ++i2) {
        int c = i2 * 64 + lane;
        int row = c >> 3, col = (c & 7) * 8;
        u16x8 v = *(const u16x8*)&Ot[row * 72 + col];
        *(u16x8*)(Ob + (long)(b * SEQ + q0w + row) * DM + h * DK + col) = v;
    }
}

extern "C" void kernel_launch(void* const* d_in, const int* in_sizes, int n_in,
                              void* d_out, int out_size, void* d_ws, size_t ws_size,
                              hipStream_t stream) {
    const float* x = (const float*)d_in[0];
    const float* Wq = (const float*)d_in[1];
    const float* Wk = (const float*)d_in[2];
    const float* Wv = (const float*)d_in[3];
    const float* Wo = (const float*)d_in[4];
    float* out = (float*)d_out;

    const int M = 2 * SEQ;  // 4096 rows
    char* p = (char*)d_ws;
    u16* xb = (u16*)p;      p += (size_t)M * DM * 2;          // 8 MB
    u16* WqbT = (u16*)p;    p += (size_t)DM * DM * 2;         // 2 MB
    u16* WkvT = (u16*)p;    p += (size_t)2 * DK * DM * 2;     // 256 KB (K rows then V rows)
    u16* WobT = (u16*)p;    p += (size_t)DM * DM * 2;         // 2 MB
    float* KVf = (float*)p; p += (size_t)M * 128 * 4;         // 2 MB (cols 0-63 K, 64-127 V)
    u16* Qb = (u16*)p;      p += (size_t)M * DM * 2;          // 8 MB
    u16* Kb = (u16*)p;      p += (size_t)M * DK * 2;          // 512 KB
    u16* VbT = (u16*)p;     p += (size_t)M * DK * 2;          // 512 KB
    u16* Ob = (u16*)p;      p += (size_t)M * DM * 2;          // 8 MB
    float2* tab = (float2*)p; p += (size_t)SEQ * 32 * 8;      // 512 KB sincos table

    // 1) convert inputs to bf16 (+ weight transposes + sincos table)
    k_cvt_bf16<<<(M * DM / 4 + 255) / 256, 256, 0, stream>>>(x, xb, M * DM / 4);
    k_trig<<<(SEQ * 32) / 256, 256, 0, stream>>>(tab);
    k_transpose<<<dim3(DM / 32, DM / 32), 256, 0, stream>>>(Wq, WqbT, DM, DM, DM);
    k_transpose<<<dim3(DK / 32, DM / 32), 256, 0, stream>>>(Wk, WkvT, DK, DM, DK);
    k_transpose<<<dim3(DK / 32, DM / 32), 256, 0, stream>>>(Wv, WkvT + (size_t)DK * DM, DK, DM, DK);
    k_transpose<<<dim3(DM / 32, DM / 32), 256, 0, stream>>>(Wo, WobT, DM, DM, DM);

    // 2) projections: Q with fused table-RoPE -> bf16 Qb; K,V fused as N=128 -> f32
    k_gemmQ<<<dim3(DM / 128, M / 128), 256, 0, stream>>>(xb, WqbT, tab, Qb);
    k_gemm128<<<dim3(1, M / 128), 256, 0, stream>>>(xb, WkvT, KVf, 128, DM);

    // 3) RoPE-K (table) + V transpose (to bf16)
    k_rope_k<<<(M * 32) / 256, 256, 0, stream>>>(KVf, tab, Kb);
    for (int bb = 0; bb < 2; ++bb)
        k_transpose<<<dim3(DK / 32, SEQ / 32), 256, 0, stream>>>(
            KVf + (size_t)bb * SEQ * 128 + DK, VbT + (size_t)bb * DK * SEQ, 128, SEQ, DK);

    // 4) attention (ring-3 counted-vmcnt pipeline, fast exp2)
    k_attn<<<dim3(2 * NH * (SEQ / 128)), 256, 0, stream>>>(Qb, Kb, VbT, Ob);

    // 5) output projection -> d_out
    k_gemm128<<<dim3(DM / 128, M / 128), 256, 0, stream>>>(Ob, WobT, out, DM, DM);
}

// Round 11
// 134.848 us; speedup vs baseline: 1.1774x; 1.1522x over previous
//
#include <hip/hip_runtime.h>

#define DM 1024
#define NH 16
#define DK 64
#define SEQ 2048

typedef __attribute__((ext_vector_type(8))) __bf16 bf16x8;
typedef __attribute__((ext_vector_type(4))) float f32x4;
typedef __attribute__((ext_vector_type(16))) float f32x16;
typedef __attribute__((ext_vector_type(8))) unsigned short u16x8;
typedef __attribute__((ext_vector_type(4))) unsigned int u32x4;
typedef unsigned short u16;

#define MFMA(a, b, c) __builtin_amdgcn_mfma_f32_16x16x32_bf16(a, b, c, 0, 0, 0)
#define MFMA32(a, b, c) __builtin_amdgcn_mfma_f32_32x32x16_bf16(a, b, c, 0, 0, 0)

__device__ __forceinline__ u16 f2bf(float f) {
    unsigned u = __builtin_bit_cast(unsigned, f);
    u = (u + 0x7FFFu + ((u >> 16) & 1u)) >> 16;
    return (u16)u;
}

__device__ __forceinline__ bf16x8 ldb(const u16* p) {
    u16x8 v = *(const u16x8*)p;
    return __builtin_bit_cast(bf16x8, v);
}

__device__ __forceinline__ unsigned cvtpk(float a, float b) {
    unsigned r;
    asm("v_cvt_pk_bf16_f32 %0, %1, %2" : "=v"(r) : "v"(a), "v"(b));
    return r;
}

__device__ __forceinline__ void swap32(unsigned& a, unsigned& b) {
    asm volatile("v_permlane32_swap_b32 %0, %1" : "+v"(a), "+v"(b));
}

__device__ __forceinline__ float fexp2(float x) {
    return __builtin_amdgcn_exp2f(x);
}

// async global->LDS, 16B per lane, LDS dest = wave-uniform base + lane*16
__device__ __forceinline__ void gload16(const u16* g, u16* l) {
    __builtin_amdgcn_global_load_lds(
        (const __attribute__((address_space(1))) unsigned int*)g,
        (__attribute__((address_space(3))) unsigned int*)l, 16, 0, 0);
}

// ================= fused prep: cvt + trig table + 4 weight transposes =================
#define NB_CVT 4096
#define NB_TRIG 256
#define NB_TQ 1024
#define NB_TK 64
#define NB_TV 64
#define NB_TO 1024

__device__ __forceinline__ void do_transpose(const float* __restrict__ W,
                                             u16* __restrict__ WT, int ldW, int K,
                                             int bx, int by, float (*t)[33]) {
    int n0 = bx * 32, k0 = by * 32;
    int tx = threadIdx.x & 31, ty = threadIdx.x >> 5;
#pragma unroll
    for (int i = 0; i < 32; i += 8)
        t[ty + i][tx] = W[(long)(k0 + ty + i) * ldW + n0 + tx];
    __syncthreads();
#pragma unroll
    for (int i = 0; i < 32; i += 8)
        WT[(long)(n0 + ty + i) * K + k0 + tx] = f2bf(t[tx][ty + i]);
}

__global__ __launch_bounds__(256) void k_prep(const float* __restrict__ x,
                                              u16* __restrict__ xb,
                                              float2* __restrict__ tab,
                                              const float* __restrict__ Wq,
                                              u16* __restrict__ WqbT,
                                              const float* __restrict__ Wk,
                                              const float* __restrict__ Wv,
                                              u16* __restrict__ WkvT,
                                              const float* __restrict__ Wo,
                                              u16* __restrict__ WobT) {
    __shared__ float tsh[32][33];
    int blk = blockIdx.x;
    if (blk < NB_CVT) {  // f32 -> bf16 convert, x4 vectorized
        int i = blk * 256 + threadIdx.x;
        float4 v = ((const float4*)x)[i];
        ushort4 o;
        o.x = f2bf(v.x); o.y = f2bf(v.y); o.z = f2bf(v.z); o.w = f2bf(v.w);
        ((ushort4*)xb)[i] = o;
        return;
    }
    blk -= NB_CVT;
    if (blk < NB_TRIG) {  // sincos table tab[s][i]
        int idx = blk * 256 + threadIdx.x;
        int i = idx & 31, s = idx >> 5;
        float theta = exp2f(-(float)i * 0.4152410118609203f);  // 10000^(-2i/64)
        float sn, cs;
        sincosf((float)s * theta, &sn, &cs);
        tab[idx] = make_float2(cs, sn);
        return;
    }
    blk -= NB_TRIG;
    if (blk < NB_TQ) { do_transpose(Wq, WqbT, DM, DM, blk & 31, blk >> 5, tsh); return; }
    blk -= NB_TQ;
    if (blk < NB_TK) { do_transpose(Wk, WkvT, DK, DM, blk & 1, blk >> 1, tsh); return; }
    blk -= NB_TK;
    if (blk < NB_TV) { do_transpose(Wv, WkvT + (size_t)DK * DM, DK, DM, blk & 1, blk >> 1, tsh); return; }
    blk -= NB_TV;
    do_transpose(Wo, WobT, DM, DM, blk & 31, blk >> 5, tsh);
}

// ========== ring-3 GEMM, counted vmcnt: C[M][N] = A[M][K=1024] * BT[N][K]^T ==========
// 128x128 tile, BK=64, 96KB dynamic LDS (3 bufs). Per wave 8 gload16/K-step ->
// steady vmcnt(16) = 2 K-steps in flight. EPI: 0 = f32 C (N=1024);
// 1 = fused RoPE-Q -> bf16 (N=1024); 2 = KV: RoPE-K -> Kb + V -> VbT (N=128).
template <int EPI>
__global__ __launch_bounds__(256) void k_gemm_r3(const u16* __restrict__ A,
                                                 const u16* __restrict__ BT,
                                                 void* __restrict__ out0,
                                                 void* __restrict__ out1,
                                                 const float2* __restrict__ tab) {
    extern __shared__ __align__(16) u16 lds[];  // [3][A:8192 | B:8192]
    const int NT = 16;                          // K=1024 / 64
    const int K = DM;
    int tid = threadIdx.x;
    int w = tid >> 6, lane = tid & 63, lg = lane >> 4, lr = lane & 15;
    int wr = w >> 1, wc = w & 1;
    long m0 = (long)blockIdx.y * 128, n0 = (long)blockIdx.x * 128;
    int lrow = lane >> 3, lcol = (lane & 7) * 8;

    f32x4 acc[4][4] = {};

#define GSTAGE(t)                                                                   \
    {                                                                               \
        u16* as_ = lds + ((t) % 3) * 8192;                                          \
        u16* bs_ = lds + 24576 + ((t) % 3) * 8192;                                  \
        int k0_ = (t) * 64;                                                         \
        _Pragma("unroll") for (int it = 0; it < 4; ++it) {                          \
            int row = w * 32 + it * 8;                                              \
            gload16(A + (m0 + row + lrow) * K + k0_ + lcol, as_ + row * 64);        \
            gload16(BT + (n0 + row + lrow) * K + k0_ + lcol, bs_ + row * 64);       \
        }                                                                           \
    }

    GSTAGE(0);
    GSTAGE(1);
    for (int t = 0; t < NT; ++t) {
        if (t + 2 < NT) {
            GSTAGE(t + 2);
            asm volatile("s_waitcnt vmcnt(16)" ::: "memory");  // K-step t landed (mine)
        } else if (t + 1 < NT) {
            asm volatile("s_waitcnt vmcnt(8)" ::: "memory");
        } else {
            asm volatile("s_waitcnt vmcnt(0)" ::: "memory");
        }
        __builtin_amdgcn_s_barrier();  // K-step t landed (all waves)
        const u16* as = lds + (t % 3) * 8192;
        const u16* bs = lds + 24576 + (t % 3) * 8192;
#pragma unroll
        for (int kk = 0; kk < 64; kk += 32) {
            bf16x8 af[4], bf[4];
#pragma unroll
            for (int i = 0; i < 4; ++i) {
                af[i] = ldb(as + (wr * 64 + i * 16 + lr) * 64 + kk + lg * 8);
                bf[i] = ldb(bs + (wc * 64 + i * 16 + lr) * 64 + kk + lg * 8);
            }
#pragma unroll
            for (int mi = 0; mi < 4; ++mi)
#pragma unroll
                for (int ni = 0; ni < 4; ++ni)
                    acc[mi][ni] = MFMA(af[mi], bf[ni], acc[mi][ni]);
        }
        __builtin_amdgcn_s_barrier();  // all done reading buf t%3 before overwrite
    }
#undef GSTAGE

    if (EPI == 0) {  // plain f32 C, N=1024
        float* C = (float*)out0;
#pragma unroll
        for (int mi = 0; mi < 4; ++mi)
#pragma unroll
            for (int ni = 0; ni < 4; ++ni)
#pragma unroll
                for (int r = 0; r < 4; ++r) {
                    long row = m0 + wr * 64 + mi * 16 + lg * 4 + r;
                    long col = n0 + wc * 64 + ni * 16 + lr;
                    C[row * DM + col] = acc[mi][ni][r];
                }
    } else if (EPI == 1) {  // fused RoPE-Q (scaled by 0.125*log2e) -> bf16
        u16* Qb = (u16*)out0;
        const float SC = 0.18033688011112042f;
#pragma unroll
        for (int ni = 0; ni < 4; ++ni) {
            int col = (int)n0 + wc * 64 + ni * 16 + lr;
            int ii = (col & 63) >> 1;
#pragma unroll
            for (int mi = 0; mi < 4; ++mi) {
                long row0 = m0 + wr * 64 + mi * 16 + lg * 4;
#pragma unroll
                for (int r = 0; r < 4; ++r) {
                    int s = (int)(row0 + r) & (SEQ - 1);
                    float2 t = tab[s * 32 + ii];
                    float mine = acc[mi][ni][r];
                    float other = __shfl_xor(mine, 1);
                    float o = ((col & 1) ? (mine * t.x + other * t.y)
                                         : (mine * t.x - other * t.y)) * SC;
                    float oo = __shfl_xor(o, 1);
                    if (!(lr & 1))
                        *(unsigned*)(Qb + (row0 + r) * DM + col) = cvtpk(o, oo);
                }
            }
        }
    } else {  // EPI == 2: cols 0-63 = K (RoPE, unscaled), cols 64-127 = V (transposed)
        u16* Kb = (u16*)out0;
        u16* VbT = (u16*)out1;
        if (wc == 0) {  // K half
#pragma unroll
            for (int ni = 0; ni < 4; ++ni) {
                int col = ni * 16 + lr;  // 0..63
                int ii = col >> 1;
#pragma unroll
                for (int mi = 0; mi < 4; ++mi) {
                    long row0 = m0 + wr * 64 + mi * 16 + lg * 4;
#pragma unroll
                    for (int r = 0; r < 4; ++r) {
                        int s = (int)(row0 + r) & (SEQ - 1);
                        float2 t = tab[s * 32 + ii];
                        float mine = acc[mi][ni][r];
                        float other = __shfl_xor(mine, 1);
                        float o = (col & 1) ? (mine * t.x + other * t.y)
                                            : (mine * t.x - other * t.y);
                        float oo = __shfl_xor(o, 1);
                        if (!(lr & 1))
                            *(unsigned*)(Kb + (row0 + r) * DK + col) = cvtpk(o, oo);
                    }
                }
            }
        } else {  // V half -> VbT[b][d][s]
#pragma unroll
            for (int ni = 0; ni < 4; ++ni) {
                int d = ni * 16 + lr;  // 0..63
#pragma unroll
                for (int mi = 0; mi < 4; ++mi) {
                    long row0 = m0 + wr * 64 + mi * 16 + lg * 4;
#pragma unroll
                    for (int r = 0; r < 4; ++r) {
                        long row = row0 + r;
                        long bb = row >> 11;
                        int s = (int)row & (SEQ - 1);
                        VbT[bb * DK * SEQ + (long)d * SEQ + s] = f2bf(acc[mi][ni][r]);
                    }
                }
            }
        }
    }
}

// ============ attention: 4 waves x 32 q-rows, ring-4 LDS, single barrier/tile ============
// LDS tile = [64 rows][64 bf16]. Swizzle: 16B slot ^= (row&7); staging uses linear
// LDS dest + inverse-swizzled GLOBAL source (rule #21).
__device__ __forceinline__ void stage2(u16* dst, const u16* src0, long rstride,
                                       int w, int lane) {
#pragma unroll
    for (int pp = 0; pp < 2; ++pp) {
        int p = w + pp * 4;
        int row = p * 8 + (lane >> 3), slot = lane & 7;
        gload16(src0 + (long)row * rstride + ((slot ^ (row & 7)) * 8), dst + p * 512);
    }
}

__device__ __forceinline__ bf16x8 lds_frag(const u16* tile, int row, int slot) {
    return ldb(tile + row * 64 + ((slot ^ (row & 7)) * 8));
}

// Swapped QK^T: S^T[kv][q] = mfma(K, Q^T); crow(r,hi) = (r&3) + 8*(r>>2) + 4*hi.
// Swapped PV: O^T[d][q] = mfma(V^T, P^T). log2-domain softmax, deferred max (T13).
template <bool MASKED>
__device__ __forceinline__ void attn_tile(int kv0, int q, int lq, int hi,
                                          const u16* Kt, const u16* Vt,
                                          const bf16x8 qf[4],
                                          f32x16& o0, f32x16& o1,
                                          float& m, float& lsum) {
    f32x16 s0 = {}, s1 = {};
    __builtin_amdgcn_s_setprio(1);
#pragma unroll
    for (int ks = 0; ks < 4; ++ks) {
        s0 = MFMA32(lds_frag(Kt, lq, hi + 2 * ks), qf[ks], s0);
        s1 = MFMA32(lds_frag(Kt, lq + 32, hi + 2 * ks), qf[ks], s1);
    }
    __builtin_amdgcn_s_setprio(0);
    if (MASKED) {
#pragma unroll
        for (int r = 0; r < 16; ++r) {
            int crow = (r & 3) + 8 * (r >> 2) + 4 * hi;
            if (kv0 + crow > q) s0[r] = -3e38f;
            if (kv0 + 32 + crow > q) s1[r] = -3e38f;
        }
    }
    float t[8];
#pragma unroll
    for (int j = 0; j < 8; ++j)
        t[j] = fmaxf(fmaxf(s0[j], s0[j + 8]), fmaxf(s1[j], s1[j + 8]));
    float pmax = fmaxf(fmaxf(fmaxf(t[0], t[4]), fmaxf(t[1], t[5])),
                       fmaxf(fmaxf(t[2], t[6]), fmaxf(t[3], t[7])));
    pmax = fmaxf(pmax, __shfl_xor(pmax, 32));
    if (__any(pmax > m + 8.f)) {
        float mnew = fmaxf(m, pmax);
        float fac = fexp2(m - mnew);
        m = mnew;
        lsum *= fac;
        o0 *= fac;
        o1 *= fac;
    }
    float p0[16], p1[16];
#pragma unroll
    for (int r = 0; r < 16; ++r) {
        p0[r] = fexp2(s0[r] - m);
        p1[r] = fexp2(s1[r] - m);
    }
    float su[8];
#pragma unroll
    for (int j = 0; j < 8; ++j)
        su[j] = (p0[j] + p0[j + 8]) + (p1[j] + p1[j + 8]);
    float psum = ((su[0] + su[4]) + (su[1] + su[5])) + ((su[2] + su[6]) + (su[3] + su[7]));
    psum += __shfl_xor(psum, 32);
    lsum += psum;
    bf16x8 pa[4];
#pragma unroll
    for (int g = 0; g < 2; ++g) {
        unsigned a0 = cvtpk(p0[g * 8 + 0], p0[g * 8 + 1]);
        unsigned b0 = cvtpk(p0[g * 8 + 4], p0[g * 8 + 5]);
        swap32(a0, b0);
        unsigned a1 = cvtpk(p0[g * 8 + 2], p0[g * 8 + 3]);
        unsigned b1 = cvtpk(p0[g * 8 + 6], p0[g * 8 + 7]);
        swap32(a1, b1);
        u32x4 u = {a0, a1, b0, b1};
        pa[g] = __builtin_bit_cast(bf16x8, u);
    }
#pragma unroll
    for (int g = 0; g < 2; ++g) {
        unsigned a0 = cvtpk(p1[g * 8 + 0], p1[g * 8 + 1]);
        unsigned b0 = cvtpk(p1[g * 8 + 4], p1[g * 8 + 5]);
        swap32(a0, b0);
        unsigned a1 = cvtpk(p1[g * 8 + 2], p1[g * 8 + 3]);
        unsigned b1 = cvtpk(p1[g * 8 + 6], p1[g * 8 + 7]);
        swap32(a1, b1);
        u32x4 u = {a0, a1, b0, b1};
        pa[2 + g] = __builtin_bit_cast(bf16x8, u);
    }
    __builtin_amdgcn_s_setprio(1);
#pragma unroll
    for (int ks = 0; ks < 4; ++ks) {
        o0 = MFMA32(lds_frag(Vt, lq, hi + 2 * ks), pa[ks], o0);
        o1 = MFMA32(lds_frag(Vt, lq + 32, hi + 2 * ks), pa[ks], o1);
    }
    __builtin_amdgcn_s_setprio(0);
}

// grid: flat 512 blocks (256 thr = 4 waves, 128 q-rows). Ring-4 + ONE barrier per
// tile: stage(t+2) -> counted vmcnt(own t) -> barrier -> compute(t). Write of tile
// j is after barrier_{j-3}; the last read of that buffer (tile j-4) completed
// before every wave reached barrier_{j-3} -> race-free.
__global__ __launch_bounds__(256) void k_attn(const u16* __restrict__ Qb,
                                              const u16* __restrict__ Kb,
                                              const u16* __restrict__ VbT,
                                              u16* __restrict__ Ob) {
    __shared__ __align__(16) u16 lds[4][2][4096];  // [ring][K/V][64x64 bf16] = 64KB
    int id = blockIdx.x;
    int h = id & 15, b = (id >> 4) & 1;
    int qslot = id >> 5;                               // 0..15
    int qt = qslot < 8 ? qslot * 2 : 31 - qslot * 2;   // pair-balanced bijection
    int qb0 = qt * 128;
    int w = threadIdx.x >> 6, lane = threadIdx.x & 63;
    int lq = lane & 31, hi = lane >> 5;
    int q0w = qb0 + 32 * w;
    int q = q0w + lq;
    const u16* Qp = Qb + (long)(b * SEQ + q) * DM + h * DK + hi * 8;
    bf16x8 qf[4];
#pragma unroll
    for (int ks = 0; ks < 4; ++ks) qf[ks] = ldb(Qp + ks * 16);
    const u16* Kbase = Kb + (long)b * SEQ * DK;
    const u16* Vbase = VbT + (long)b * DK * SEQ;
    f32x16 o0 = {}, o1 = {};
    float m = -1e30f, lsum = 0.f;

    int nt = (qb0 >> 6) + 2;  // 64-kv tiles covering [0, qb0+128); nt >= 2
    stage2(&lds[0][0][0], Kbase, DK, w, lane);
    stage2(&lds[0][1][0], Vbase, SEQ, w, lane);
    stage2(&lds[1][0][0], Kbase + (long)64 * DK, DK, w, lane);
    stage2(&lds[1][1][0], Vbase + 64, SEQ, w, lane);
    for (int t = 0; t < nt; ++t) {
        int kv0 = t * 64;
        if (t + 2 < nt) {
            int bi2 = (t + 2) & 3;
            stage2(&lds[bi2][0][0], Kbase + (long)(kv0 + 128) * DK, DK, w, lane);
            stage2(&lds[bi2][1][0], Vbase + kv0 + 128, SEQ, w, lane);
            asm volatile("s_waitcnt vmcnt(8)" ::: "memory");  // tile t landed (mine)
        } else if (t + 1 < nt) {
            asm volatile("s_waitcnt vmcnt(4)" ::: "memory");
        } else {
            asm volatile("s_waitcnt vmcnt(0)" ::: "memory");
        }
        __builtin_amdgcn_s_barrier();  // tile t landed (all waves)
        int bi = t & 3;
        if (kv0 <= q0w + 31) {
            if (kv0 + 63 <= q0w)
                attn_tile<false>(kv0, q, lq, hi, &lds[bi][0][0], &lds[bi][1][0],
                                 qf, o0, o1, m, lsum);
            else
                attn_tile<true>(kv0, q, lq, hi, &lds[bi][0][0], &lds[bi][1][0],
                                qf, o0, o1, m, lsum);
        }
    }
    __syncthreads();  // all waves done with ring before Ot reuse

    float linv = 1.f / lsum;
    u16* Ot = &lds[0][0][0] + w * 2304;  // 32 x 72 u16 per wave
#pragma unroll
    for (int rq = 0; rq < 4; ++rq) {
        uint2 u0, u1;
        u0.x = cvtpk(o0[4 * rq + 0] * linv, o0[4 * rq + 1] * linv);
        u0.y = cvtpk(o0[4 * rq + 2] * linv, o0[4 * rq + 3] * linv);
        u1.x = cvtpk(o1[4 * rq + 0] * linv, o1[4 * rq + 1] * linv);
        u1.y = cvtpk(o1[4 * rq + 2] * linv, o1[4 * rq + 3] * linv);
        *(uint2*)&Ot[lq * 72 + rq * 8 + hi * 4] = u0;
        *(uint2*)&Ot[lq * 72 + 32 + rq * 8 + hi * 4] = u1;
    }
#pragma unroll
    for (int i2 = 0; i2 < 4; ++i2) {
        int c = i2 * 64 + lane;
        int row = c >> 3, col = (c & 7) * 8;
        u16x8 v = *(const u16x8*)&Ot[row * 72 + col];
        *(u16x8*)(Ob + (long)(b * SEQ + q0w + row) * DM + h * DK + col) = v;
    }
}

extern "C" void kernel_launch(void* const* d_in, const int* in_sizes, int n_in,
                              void* d_out, int out_size, void* d_ws, size_t ws_size,
                              hipStream_t stream) {
    const float* x = (const float*)d_in[0];
    const float* Wq = (const float*)d_in[1];
    const float* Wk = (const float*)d_in[2];
    const float* Wv = (const float*)d_in[3];
    const float* Wo = (const float*)d_in[4];
    float* out = (float*)d_out;

    const int M = 2 * SEQ;  // 4096 rows
    char* p = (char*)d_ws;
    u16* xb = (u16*)p;        p += (size_t)M * DM * 2;       // 8 MB
    u16* WqbT = (u16*)p;      p += (size_t)DM * DM * 2;      // 2 MB
    u16* WkvT = (u16*)p;      p += (size_t)2 * DK * DM * 2;  // 256 KB
    u16* WobT = (u16*)p;      p += (size_t)DM * DM * 2;      // 2 MB
    u16* Qb = (u16*)p;        p += (size_t)M * DM * 2;       // 8 MB
    u16* Kb = (u16*)p;        p += (size_t)M * DK * 2;       // 512 KB
    u16* VbT = (u16*)p;       p += (size_t)M * DK * 2;       // 512 KB
    u16* Ob = (u16*)p;        p += (size_t)M * DM * 2;       // 8 MB
    float2* tab = (float2*)p; p += (size_t)SEQ * 32 * 8;     // 512 KB

    const size_t GEMM_LDS = 3 * 2 * 8192 * sizeof(u16);  // 96 KB

    // 1) fused prep: cvt + trig + 4 weight transposes (one launch)
    k_prep<<<NB_CVT + NB_TRIG + NB_TQ + NB_TK + NB_TV + NB_TO, 256, 0, stream>>>(
        x, xb, tab, Wq, WqbT, Wk, Wv, WkvT, Wo, WobT);

    // 2) Q projection + fused RoPE -> bf16 Qb
    k_gemm_r3<1><<<dim3(DM / 128, M / 128), 256, GEMM_LDS, stream>>>(
        xb, WqbT, Qb, nullptr, tab);

    // 3) KV projection + fused RoPE-K -> Kb and V-transpose -> VbT
    k_gemm_r3<2><<<dim3(1, M / 128), 256, GEMM_LDS, stream>>>(
        xb, WkvT, Kb, VbT, tab);

    // 4) attention (ring-4, single barrier per tile)
    k_attn<<<dim3(2 * NH * (SEQ / 128)), 256, 0, stream>>>(Qb, Kb, VbT, Ob);

    // 5) output projection -> d_out
    k_gemm_r3<0><<<dim3(DM / 128, M / 128), 256, GEMM_LDS, stream>>>(
        Ob, WobT, out, nullptr, nullptr);
}

// Round 12
// 107.427 us; speedup vs baseline: 1.4779x; 1.2553x over previous
//
#include <hip/hip_runtime.h>

#define DM 1024
#define NH 16
#define DK 64
#define SEQ 2048

typedef __attribute__((ext_vector_type(8))) __bf16 bf16x8;
typedef __attribute__((ext_vector_type(4))) float f32x4;
typedef __attribute__((ext_vector_type(16))) float f32x16;
typedef __attribute__((ext_vector_type(8))) unsigned short u16x8;
typedef __attribute__((ext_vector_type(4))) unsigned int u32x4;
typedef unsigned short u16;

#define MFMA(a, b, c) __builtin_amdgcn_mfma_f32_16x16x32_bf16(a, b, c, 0, 0, 0)
#define MFMA32(a, b, c) __builtin_amdgcn_mfma_f32_32x32x16_bf16(a, b, c, 0, 0, 0)

__device__ __forceinline__ u16 f2bf(float f) {
    unsigned u = __builtin_bit_cast(unsigned, f);
    u = (u + 0x7FFFu + ((u >> 16) & 1u)) >> 16;
    return (u16)u;
}

__device__ __forceinline__ bf16x8 ldb(const u16* p) {
    u16x8 v = *(const u16x8*)p;
    return __builtin_bit_cast(bf16x8, v);
}

__device__ __forceinline__ unsigned cvtpk(float a, float b) {
    unsigned r;
    asm("v_cvt_pk_bf16_f32 %0, %1, %2" : "=v"(r) : "v"(a), "v"(b));
    return r;
}

__device__ __forceinline__ void swap32(unsigned& a, unsigned& b) {
    asm volatile("v_permlane32_swap_b32 %0, %1" : "+v"(a), "+v"(b));
}

__device__ __forceinline__ float fexp2(float x) {
    return __builtin_amdgcn_exp2f(x);
}

// async global->LDS, 16B per lane, LDS dest = wave-uniform base + lane*16
__device__ __forceinline__ void gload16(const u16* g, u16* l) {
    __builtin_amdgcn_global_load_lds(
        (const __attribute__((address_space(1))) unsigned int*)g,
        (__attribute__((address_space(3))) unsigned int*)l, 16, 0, 0);
}

// ================= fused prep: cvt + trig table + 4 weight transposes =================
#define NB_CVT 4096
#define NB_TRIG 256
#define NB_TQ 1024
#define NB_TK 64
#define NB_TV 64
#define NB_TO 1024

__device__ __forceinline__ void do_transpose(const float* __restrict__ W,
                                             u16* __restrict__ WT, int ldW, int K,
                                             int bx, int by, float (*t)[33]) {
    int n0 = bx * 32, k0 = by * 32;
    int tx = threadIdx.x & 31, ty = threadIdx.x >> 5;
#pragma unroll
    for (int i = 0; i < 32; i += 8)
        t[ty + i][tx] = W[(long)(k0 + ty + i) * ldW + n0 + tx];
    __syncthreads();
#pragma unroll
    for (int i = 0; i < 32; i += 8)
        WT[(long)(n0 + ty + i) * K + k0 + tx] = f2bf(t[tx][ty + i]);
}

__global__ __launch_bounds__(256) void k_prep(const float* __restrict__ x,
                                              u16* __restrict__ xb,
                                              float2* __restrict__ tab,
                                              const float* __restrict__ Wq,
                                              const float* __restrict__ Wk,
                                              const float* __restrict__ Wv,
                                              u16* __restrict__ WqkvT,
                                              const float* __restrict__ Wo,
                                              u16* __restrict__ WobT) {
    __shared__ float tsh[32][33];
    int blk = blockIdx.x;
    if (blk < NB_CVT) {  // f32 -> bf16 convert, x4 vectorized
        int i = blk * 256 + threadIdx.x;
        float4 v = ((const float4*)x)[i];
        ushort4 o;
        o.x = f2bf(v.x); o.y = f2bf(v.y); o.z = f2bf(v.z); o.w = f2bf(v.w);
        ((ushort4*)xb)[i] = o;
        return;
    }
    blk -= NB_CVT;
    if (blk < NB_TRIG) {  // sincos table tab[s][i]
        int idx = blk * 256 + threadIdx.x;
        int i = idx & 31, s = idx >> 5;
        float theta = exp2f(-(float)i * 0.4152410118609203f);  // 10000^(-2i/64)
        float sn, cs;
        sincosf((float)s * theta, &sn, &cs);
        tab[idx] = make_float2(cs, sn);
        return;
    }
    blk -= NB_TRIG;
    if (blk < NB_TQ) { do_transpose(Wq, WqkvT, DM, DM, blk & 31, blk >> 5, tsh); return; }
    blk -= NB_TQ;
    if (blk < NB_TK) { do_transpose(Wk, WqkvT + (size_t)DM * DM, DK, DM, blk & 1, blk >> 1, tsh); return; }
    blk -= NB_TK;
    if (blk < NB_TV) { do_transpose(Wv, WqkvT + (size_t)(DM + DK) * DM, DK, DM, blk & 1, blk >> 1, tsh); return; }
    blk -= NB_TV;
    do_transpose(Wo, WobT, DM, DM, blk & 31, blk >> 5, tsh);
}

// ========== ring-2 GEMM, counted vmcnt: C[M][N'] = A[M][K=1024] * BT[N'][K]^T ==========
// 128x128 tile, BK=64, 64KB dynamic LDS (2 bufs -> 2 blocks/CU). Per wave 8 gload16
// per K-step; steady vmcnt(8), last step vmcnt(0); stage(t+2) after 2nd barrier.
// MODE 0: plain f32 C (N=1024). MODE 1: fused QKV epi — n-blocks 0..7 = RoPE-Q ->
// bf16 Qb; n-block 8 = RoPE-K -> Kb (cols 0-63) + V-transpose -> VbT (cols 64-127).
template <int MODE>
__global__ __launch_bounds__(256) void k_gemm_r2(const u16* __restrict__ A,
                                                 const u16* __restrict__ BT,
                                                 void* __restrict__ out0,
                                                 void* __restrict__ out1,
                                                 void* __restrict__ out2,
                                                 const float2* __restrict__ tab) {
    extern __shared__ __align__(16) u16 lds[];  // [2][A:8192] ++ [2][B:8192]
    const int NT = 16;                          // K=1024 / 64
    const int K = DM;
    int tid = threadIdx.x;
    int w = tid >> 6, lane = tid & 63, lg = lane >> 4, lr = lane & 15;
    int wr = w >> 1, wc = w & 1;
    long m0 = (long)blockIdx.y * 128, n0 = (long)blockIdx.x * 128;
    int lrow = lane >> 3, lcol = (lane & 7) * 8;

    f32x4 acc[4][4] = {};

#define GSTAGE(t)                                                                   \
    {                                                                               \
        u16* as_ = lds + ((t) & 1) * 8192;                                          \
        u16* bs_ = lds + 16384 + ((t) & 1) * 8192;                                  \
        int k0_ = (t) * 64;                                                         \
        _Pragma("unroll") for (int it = 0; it < 4; ++it) {                          \
            int row = w * 32 + it * 8;                                              \
            gload16(A + (m0 + row + lrow) * K + k0_ + lcol, as_ + row * 64);        \
            gload16(BT + (n0 + row + lrow) * K + k0_ + lcol, bs_ + row * 64);       \
        }                                                                           \
    }

    GSTAGE(0);
    GSTAGE(1);
    for (int t = 0; t < NT; ++t) {
        if (t + 1 < NT) {
            asm volatile("s_waitcnt vmcnt(8)" ::: "memory");  // K-step t landed (mine)
        } else {
            asm volatile("s_waitcnt vmcnt(0)" ::: "memory");
        }
        __builtin_amdgcn_s_barrier();  // K-step t landed (all waves)
        const u16* as = lds + (t & 1) * 8192;
        const u16* bs = lds + 16384 + (t & 1) * 8192;
#pragma unroll
        for (int kk = 0; kk < 64; kk += 32) {
            bf16x8 af[4], bf[4];
#pragma unroll
            for (int i = 0; i < 4; ++i) {
                af[i] = ldb(as + (wr * 64 + i * 16 + lr) * 64 + kk + lg * 8);
                bf[i] = ldb(bs + (wc * 64 + i * 16 + lr) * 64 + kk + lg * 8);
            }
#pragma unroll
            for (int mi = 0; mi < 4; ++mi)
#pragma unroll
                for (int ni = 0; ni < 4; ++ni)
                    acc[mi][ni] = MFMA(af[mi], bf[ni], acc[mi][ni]);
        }
        __builtin_amdgcn_s_barrier();  // all waves done reading buf t&1
        if (t + 2 < NT) GSTAGE(t + 2);  // safe: buf (t+2)&1 == t&1, just released
    }
#undef GSTAGE

    if (MODE == 0) {  // plain f32 C, N=1024
        float* C = (float*)out0;
#pragma unroll
        for (int mi = 0; mi < 4; ++mi)
#pragma unroll
            for (int ni = 0; ni < 4; ++ni)
#pragma unroll
                for (int r = 0; r < 4; ++r) {
                    long row = m0 + wr * 64 + mi * 16 + lg * 4 + r;
                    long col = n0 + wc * 64 + ni * 16 + lr;
                    C[row * DM + col] = acc[mi][ni][r];
                }
    } else if (n0 < DM) {  // fused RoPE-Q (scaled by 0.125*log2e) -> bf16
        u16* Qb = (u16*)out0;
        const float SC = 0.18033688011112042f;
#pragma unroll
        for (int ni = 0; ni < 4; ++ni) {
            int col = (int)n0 + wc * 64 + ni * 16 + lr;
            int ii = (col & 63) >> 1;
#pragma unroll
            for (int mi = 0; mi < 4; ++mi) {
                long row0 = m0 + wr * 64 + mi * 16 + lg * 4;
#pragma unroll
                for (int r = 0; r < 4; ++r) {
                    int s = (int)(row0 + r) & (SEQ - 1);
                    float2 t = tab[s * 32 + ii];
                    float mine = acc[mi][ni][r];
                    float other = __shfl_xor(mine, 1);
                    float o = ((col & 1) ? (mine * t.x + other * t.y)
                                         : (mine * t.x - other * t.y)) * SC;
                    float oo = __shfl_xor(o, 1);
                    if (!(lr & 1))
                        *(unsigned*)(Qb + (row0 + r) * DM + col) = cvtpk(o, oo);
                }
            }
        }
    } else {  // KV block: cols 0-63 = K (RoPE, unscaled), cols 64-127 = V (transposed)
        u16* Kb = (u16*)out1;
        u16* VbT = (u16*)out2;
        if (wc == 0) {  // K half
#pragma unroll
            for (int ni = 0; ni < 4; ++ni) {
                int col = ni * 16 + lr;  // 0..63
                int ii = col >> 1;
#pragma unroll
                for (int mi = 0; mi < 4; ++mi) {
                    long row0 = m0 + wr * 64 + mi * 16 + lg * 4;
#pragma unroll
                    for (int r = 0; r < 4; ++r) {
                        int s = (int)(row0 + r) & (SEQ - 1);
                        float2 t = tab[s * 32 + ii];
                        float mine = acc[mi][ni][r];
                        float other = __shfl_xor(mine, 1);
                        float o = (col & 1) ? (mine * t.x + other * t.y)
                                            : (mine * t.x - other * t.y);
                        float oo = __shfl_xor(o, 1);
                        if (!(lr & 1))
                            *(unsigned*)(Kb + (row0 + r) * DK + col) = cvtpk(o, oo);
                    }
                }
            }
        } else {  // V half -> VbT[b][d][s]
#pragma unroll
            for (int ni = 0; ni < 4; ++ni) {
                int d = ni * 16 + lr;  // 0..63
#pragma unroll
                for (int mi = 0; mi < 4; ++mi) {
                    long row0 = m0 + wr * 64 + mi * 16 + lg * 4;
#pragma unroll
                    for (int r = 0; r < 4; ++r) {
                        long row = row0 + r;
                        long bb = row >> 11;
                        int s = (int)row & (SEQ - 1);
                        VbT[bb * DK * SEQ + (long)d * SEQ + s] = f2bf(acc[mi][ni][r]);
                    }
                }
            }
        }
    }
}

// ============ attention: 4 waves x 32 q-rows, ring-4 LDS, single barrier/tile ============
__device__ __forceinline__ void stage2(u16* dst, const u16* src0, long rstride,
                                       int w, int lane) {
#pragma unroll
    for (int pp = 0; pp < 2; ++pp) {
        int p = w + pp * 4;
        int row = p * 8 + (lane >> 3), slot = lane & 7;
        gload16(src0 + (long)row * rstride + ((slot ^ (row & 7)) * 8), dst + p * 512);
    }
}

__device__ __forceinline__ bf16x8 lds_frag(const u16* tile, int row, int slot) {
    return ldb(tile + row * 64 + ((slot ^ (row & 7)) * 8));
}

// Swapped QK^T: S^T[kv][q] = mfma(K, Q^T); crow(r,hi) = (r&3) + 8*(r>>2) + 4*hi.
// Swapped PV: O^T[d][q] = mfma(V^T, P^T). log2-domain softmax, deferred max (T13).
template <bool MASKED>
__device__ __forceinline__ void attn_tile(int kv0, int q, int lq, int hi,
                                          const u16* Kt, const u16* Vt,
                                          const bf16x8 qf[4],
                                          f32x16& o0, f32x16& o1,
                                          float& m, float& lsum) {
    f32x16 s0 = {}, s1 = {};
    __builtin_amdgcn_s_setprio(1);
#pragma unroll
    for (int ks = 0; ks < 4; ++ks) {
        s0 = MFMA32(lds_frag(Kt, lq, hi + 2 * ks), qf[ks], s0);
        s1 = MFMA32(lds_frag(Kt, lq + 32, hi + 2 * ks), qf[ks], s1);
    }
    __builtin_amdgcn_s_setprio(0);
    if (MASKED) {
#pragma unroll
        for (int r = 0; r < 16; ++r) {
            int crow = (r & 3) + 8 * (r >> 2) + 4 * hi;
            if (kv0 + crow > q) s0[r] = -3e38f;
            if (kv0 + 32 + crow > q) s1[r] = -3e38f;
        }
    }
    float t[8];
#pragma unroll
    for (int j = 0; j < 8; ++j)
        t[j] = fmaxf(fmaxf(s0[j], s0[j + 8]), fmaxf(s1[j], s1[j + 8]));
    float pmax = fmaxf(fmaxf(fmaxf(t[0], t[4]), fmaxf(t[1], t[5])),
                       fmaxf(fmaxf(t[2], t[6]), fmaxf(t[3], t[7])));
    pmax = fmaxf(pmax, __shfl_xor(pmax, 32));
    if (__any(pmax > m + 8.f)) {
        float mnew = fmaxf(m, pmax);
        float fac = fexp2(m - mnew);
        m = mnew;
        lsum *= fac;
        o0 *= fac;
        o1 *= fac;
    }
    float p0[16], p1[16];
#pragma unroll
    for (int r = 0; r < 16; ++r) {
        p0[r] = fexp2(s0[r] - m);
        p1[r] = fexp2(s1[r] - m);
    }
    float su[8];
#pragma unroll
    for (int j = 0; j < 8; ++j)
        su[j] = (p0[j] + p0[j + 8]) + (p1[j] + p1[j + 8]);
    float psum = ((su[0] + su[4]) + (su[1] + su[5])) + ((su[2] + su[6]) + (su[3] + su[7]));
    psum += __shfl_xor(psum, 32);
    lsum += psum;
    bf16x8 pa[4];
#pragma unroll
    for (int g = 0; g < 2; ++g) {
        unsigned a0 = cvtpk(p0[g * 8 + 0], p0[g * 8 + 1]);
        unsigned b0 = cvtpk(p0[g * 8 + 4], p0[g * 8 + 5]);
        swap32(a0, b0);
        unsigned a1 = cvtpk(p0[g * 8 + 2], p0[g * 8 + 3]);
        unsigned b1 = cvtpk(p0[g * 8 + 6], p0[g * 8 + 7]);
        swap32(a1, b1);
        u32x4 u = {a0, a1, b0, b1};
        pa[g] = __builtin_bit_cast(bf16x8, u);
    }
#pragma unroll
    for (int g = 0; g < 2; ++g) {
        unsigned a0 = cvtpk(p1[g * 8 + 0], p1[g * 8 + 1]);
        unsigned b0 = cvtpk(p1[g * 8 + 4], p1[g * 8 + 5]);
        swap32(a0, b0);
        unsigned a1 = cvtpk(p1[g * 8 + 2], p1[g * 8 + 3]);
        unsigned b1 = cvtpk(p1[g * 8 + 6], p1[g * 8 + 7]);
        swap32(a1, b1);
        u32x4 u = {a0, a1, b0, b1};
        pa[2 + g] = __builtin_bit_cast(bf16x8, u);
    }
    __builtin_amdgcn_s_setprio(1);
#pragma unroll
    for (int ks = 0; ks < 4; ++ks) {
        o0 = MFMA32(lds_frag(Vt, lq, hi + 2 * ks), pa[ks], o0);
        o1 = MFMA32(lds_frag(Vt, lq + 32, hi + 2 * ks), pa[ks], o1);
    }
    __builtin_amdgcn_s_setprio(0);
}

// grid: flat 512 blocks (256 thr = 4 waves, 128 q-rows). Ring-4 + ONE barrier per
// tile (write of tile j after barrier_{j-3}; last read of that buffer before it).
__global__ __launch_bounds__(256) void k_attn(const u16* __restrict__ Qb,
                                              const u16* __restrict__ Kb,
                                              const u16* __restrict__ VbT,
                                              u16* __restrict__ Ob) {
    __shared__ __align__(16) u16 lds[4][2][4096];  // [ring][K/V][64x64 bf16] = 64KB
    int id = blockIdx.x;
    int h = id & 15, b = (id >> 4) & 1;
    int qslot = id >> 5;                               // 0..15
    int qt = qslot < 8 ? qslot * 2 : 31 - qslot * 2;   // pair-balanced bijection
    int qb0 = qt * 128;
    int w = threadIdx.x >> 6, lane = threadIdx.x & 63;
    int lq = lane & 31, hi = lane >> 5;
    int q0w = qb0 + 32 * w;
    int q = q0w + lq;
    const u16* Qp = Qb + (long)(b * SEQ + q) * DM + h * DK + hi * 8;
    bf16x8 qf[4];
#pragma unroll
    for (int ks = 0; ks < 4; ++ks) qf[ks] = ldb(Qp + ks * 16);
    const u16* Kbase = Kb + (long)b * SEQ * DK;
    const u16* Vbase = VbT + (long)b * DK * SEQ;
    f32x16 o0 = {}, o1 = {};
    float m = -1e30f, lsum = 0.f;

    int nt = (qb0 >> 6) + 2;  // 64-kv tiles covering [0, qb0+128); nt >= 2
    stage2(&lds[0][0][0], Kbase, DK, w, lane);
    stage2(&lds[0][1][0], Vbase, SEQ, w, lane);
    stage2(&lds[1][0][0], Kbase + (long)64 * DK, DK, w, lane);
    stage2(&lds[1][1][0], Vbase + 64, SEQ, w, lane);
    for (int t = 0; t < nt; ++t) {
        int kv0 = t * 64;
        if (t + 2 < nt) {
            int bi2 = (t + 2) & 3;
            stage2(&lds[bi2][0][0], Kbase + (long)(kv0 + 128) * DK, DK, w, lane);
            stage2(&lds[bi2][1][0], Vbase + kv0 + 128, SEQ, w, lane);
            asm volatile("s_waitcnt vmcnt(8)" ::: "memory");  // tile t landed (mine)
        } else if (t + 1 < nt) {
            asm volatile("s_waitcnt vmcnt(4)" ::: "memory");
        } else {
            asm volatile("s_waitcnt vmcnt(0)" ::: "memory");
        }
        __builtin_amdgcn_s_barrier();  // tile t landed (all waves)
        int bi = t & 3;
        if (kv0 <= q0w + 31) {
            if (kv0 + 63 <= q0w)
                attn_tile<false>(kv0, q, lq, hi, &lds[bi][0][0], &lds[bi][1][0],
                                 qf, o0, o1, m, lsum);
            else
                attn_tile<true>(kv0, q, lq, hi, &lds[bi][0][0], &lds[bi][1][0],
                                qf, o0, o1, m, lsum);
        }
    }
    __syncthreads();  // all waves done with ring before Ot reuse

    float linv = 1.f / lsum;
    u16* Ot = &lds[0][0][0] + w * 2304;  // 32 x 72 u16 per wave
#pragma unroll
    for (int rq = 0; rq < 4; ++rq) {
        uint2 u0, u1;
        u0.x = cvtpk(o0[4 * rq + 0] * linv, o0[4 * rq + 1] * linv);
        u0.y = cvtpk(o0[4 * rq + 2] * linv, o0[4 * rq + 3] * linv);
        u1.x = cvtpk(o1[4 * rq + 0] * linv, o1[4 * rq + 1] * linv);
        u1.y = cvtpk(o1[4 * rq + 2] * linv, o1[4 * rq + 3] * linv);
        *(uint2*)&Ot[lq * 72 + rq * 8 + hi * 4] = u0;
        *(uint2*)&Ot[lq * 72 + 32 + rq * 8 + hi * 4] = u1;
    }
#pragma unroll
    for (int i2 = 0; i2 < 4; ++i2) {
        int c = i2 * 64 + lane;
        int row = c >> 3, col = (c & 7) * 8;
        u16x8 v = *(const u16x8*)&Ot[row * 72 + col];
        *(u16x8*)(Ob + (long)(b * SEQ + q0w + row) * DM + h * DK + col) = v;
    }
}

extern "C" void kernel_launch(void* const* d_in, const int* in_sizes, int n_in,
                              void* d_out, int out_size, void* d_ws, size_t ws_size,
                              hipStream_t stream) {
    const float* x = (const float*)d_in[0];
    const float* Wq = (const float*)d_in[1];
    const float* Wk = (const float*)d_in[2];
    const float* Wv = (const float*)d_in[3];
    const float* Wo = (const float*)d_in[4];
    float* out = (float*)d_out;

    const int M = 2 * SEQ;  // 4096 rows
    char* p = (char*)d_ws;
    u16* xb = (u16*)p;        p += (size_t)M * DM * 2;          // 8 MB
    u16* WqkvT = (u16*)p;     p += (size_t)(DM + 2 * DK) * DM * 2;  // 2.25 MB
    u16* WobT = (u16*)p;      p += (size_t)DM * DM * 2;         // 2 MB
    u16* Qb = (u16*)p;        p += (size_t)M * DM * 2;          // 8 MB
    u16* Kb = (u16*)p;        p += (size_t)M * DK * 2;          // 512 KB
    u16* VbT = (u16*)p;       p += (size_t)M * DK * 2;          // 512 KB
    u16* Ob = (u16*)p;        p += (size_t)M * DM * 2;          // 8 MB
    float2* tab = (float2*)p; p += (size_t)SEQ * 32 * 8;        // 512 KB

    const size_t GEMM_LDS = 2 * 2 * 8192 * sizeof(u16);  // 64 KB -> 2 blocks/CU

    // 1) fused prep: cvt + trig + weight transposes (one launch)
    k_prep<<<NB_CVT + NB_TRIG + NB_TQ + NB_TK + NB_TV + NB_TO, 256, 0, stream>>>(
        x, xb, tab, Wq, Wk, Wv, WqkvT, Wo, WobT);

    // 2) fused QKV projection: N=1152; epi = RoPE-Q -> Qb, RoPE-K -> Kb, V^T -> VbT
    k_gemm_r2<1><<<dim3((DM + 2 * DK) / 128, M / 128), 256, GEMM_LDS, stream>>>(
        xb, WqkvT, Qb, Kb, VbT, tab);

    // 3) attention (ring-4, single barrier per tile)
    k_attn<<<dim3(2 * NH * (SEQ / 128)), 256, 0, stream>>>(Qb, Kb, VbT, Ob);

    // 4) output projection -> d_out
    k_gemm_r2<0><<<dim3(DM / 128, M / 128), 256, GEMM_LDS, stream>>>(
        Ob, WobT, out, nullptr, nullptr, nullptr);
}

// Round 13
// 99.138 us; speedup vs baseline: 1.6015x; 1.0836x over previous
//
#include <hip/hip_runtime.h>

#define DM 1024
#define NH 16
#define DK 64
#define SEQ 2048

typedef __attribute__((ext_vector_type(8))) __bf16 bf16x8;
typedef __attribute__((ext_vector_type(4))) float f32x4;
typedef __attribute__((ext_vector_type(16))) float f32x16;
typedef __attribute__((ext_vector_type(8))) unsigned short u16x8;
typedef __attribute__((ext_vector_type(4))) unsigned int u32x4;
typedef unsigned short u16;

#define MFMA(a, b, c) __builtin_amdgcn_mfma_f32_16x16x32_bf16(a, b, c, 0, 0, 0)
#define MFMA32(a, b, c) __builtin_amdgcn_mfma_f32_32x32x16_bf16(a, b, c, 0, 0, 0)

__device__ __forceinline__ u16 f2bf(float f) {
    unsigned u = __builtin_bit_cast(unsigned, f);
    u = (u + 0x7FFFu + ((u >> 16) & 1u)) >> 16;
    return (u16)u;
}

__device__ __forceinline__ bf16x8 ldb(const u16* p) {
    u16x8 v = *(const u16x8*)p;
    return __builtin_bit_cast(bf16x8, v);
}

__device__ __forceinline__ unsigned cvtpk(float a, float b) {
    unsigned r;
    asm("v_cvt_pk_bf16_f32 %0, %1, %2" : "=v"(r) : "v"(a), "v"(b));
    return r;
}

__device__ __forceinline__ void swap32(unsigned& a, unsigned& b) {
    asm volatile("v_permlane32_swap_b32 %0, %1" : "+v"(a), "+v"(b));
}

__device__ __forceinline__ float fexp2(float x) {
    return __builtin_amdgcn_exp2f(x);
}

// async global->LDS, 16B per lane, LDS dest = wave-uniform base + lane*16
__device__ __forceinline__ void gload16(const u16* g, u16* l) {
    __builtin_amdgcn_global_load_lds(
        (const __attribute__((address_space(1))) unsigned int*)g,
        (__attribute__((address_space(3))) unsigned int*)l, 16, 0, 0);
}

// ================= fused prep: cvt + trig table + 4 weight transposes =================
#define NB_CVT 4096
#define NB_TRIG 256
#define NB_TQ 1024
#define NB_TK 64
#define NB_TV 64
#define NB_TO 1024

__device__ __forceinline__ void do_transpose(const float* __restrict__ W,
                                             u16* __restrict__ WT, int ldW, int K,
                                             int bx, int by, float (*t)[33]) {
    int n0 = bx * 32, k0 = by * 32;
    int tx = threadIdx.x & 31, ty = threadIdx.x >> 5;
#pragma unroll
    for (int i = 0; i < 32; i += 8)
        t[ty + i][tx] = W[(long)(k0 + ty + i) * ldW + n0 + tx];
    __syncthreads();
#pragma unroll
    for (int i = 0; i < 32; i += 8)
        WT[(long)(n0 + ty + i) * K + k0 + tx] = f2bf(t[tx][ty + i]);
}

__global__ __launch_bounds__(256) void k_prep(const float* __restrict__ x,
                                              u16* __restrict__ xb,
                                              float2* __restrict__ tab,
                                              const float* __restrict__ Wq,
                                              const float* __restrict__ Wk,
                                              const float* __restrict__ Wv,
                                              u16* __restrict__ WqkvT,
                                              const float* __restrict__ Wo,
                                              u16* __restrict__ WobT) {
    __shared__ float tsh[32][33];
    int blk = blockIdx.x;
    if (blk < NB_CVT) {  // f32 -> bf16 convert, x4 vectorized
        int i = blk * 256 + threadIdx.x;
        float4 v = ((const float4*)x)[i];
        ushort4 o;
        o.x = f2bf(v.x); o.y = f2bf(v.y); o.z = f2bf(v.z); o.w = f2bf(v.w);
        ((ushort4*)xb)[i] = o;
        return;
    }
    blk -= NB_CVT;
    if (blk < NB_TRIG) {  // sincos table tab[s][i]
        int idx = blk * 256 + threadIdx.x;
        int i = idx & 31, s = idx >> 5;
        float theta = exp2f(-(float)i * 0.4152410118609203f);  // 10000^(-2i/64)
        float sn, cs;
        sincosf((float)s * theta, &sn, &cs);
        tab[idx] = make_float2(cs, sn);
        return;
    }
    blk -= NB_TRIG;
    if (blk < NB_TQ) { do_transpose(Wq, WqkvT, DM, DM, blk & 31, blk >> 5, tsh); return; }
    blk -= NB_TQ;
    if (blk < NB_TK) { do_transpose(Wk, WqkvT + (size_t)DM * DM, DK, DM, blk & 1, blk >> 1, tsh); return; }
    blk -= NB_TK;
    if (blk < NB_TV) { do_transpose(Wv, WqkvT + (size_t)(DM + DK) * DM, DK, DM, blk & 1, blk >> 1, tsh); return; }
    blk -= NB_TV;
    do_transpose(Wo, WobT, DM, DM, blk & 31, blk >> 5, tsh);
}

// ========== ring-2 GEMM, counted vmcnt: C[M][N'] = A[M][K=1024] * BT[N'][K]^T ==========
template <int MODE>
__global__ __launch_bounds__(256) void k_gemm_r2(const u16* __restrict__ A,
                                                 const u16* __restrict__ BT,
                                                 void* __restrict__ out0,
                                                 void* __restrict__ out1,
                                                 void* __restrict__ out2,
                                                 const float2* __restrict__ tab) {
    extern __shared__ __align__(16) u16 lds[];  // [2][A:8192] ++ [2][B:8192]
    const int NT = 16;                          // K=1024 / 64
    const int K = DM;
    int tid = threadIdx.x;
    int w = tid >> 6, lane = tid & 63, lg = lane >> 4, lr = lane & 15;
    int wr = w >> 1, wc = w & 1;
    long m0 = (long)blockIdx.y * 128, n0 = (long)blockIdx.x * 128;
    int lrow = lane >> 3, lcol = (lane & 7) * 8;

    f32x4 acc[4][4] = {};

#define GSTAGE(t)                                                                   \
    {                                                                               \
        u16* as_ = lds + ((t) & 1) * 8192;                                          \
        u16* bs_ = lds + 16384 + ((t) & 1) * 8192;                                  \
        int k0_ = (t) * 64;                                                         \
        _Pragma("unroll") for (int it = 0; it < 4; ++it) {                          \
            int row = w * 32 + it * 8;                                              \
            gload16(A + (m0 + row + lrow) * K + k0_ + lcol, as_ + row * 64);        \
            gload16(BT + (n0 + row + lrow) * K + k0_ + lcol, bs_ + row * 64);       \
        }                                                                           \
    }

    GSTAGE(0);
    GSTAGE(1);
    for (int t = 0; t < NT; ++t) {
        if (t + 1 < NT) {
            asm volatile("s_waitcnt vmcnt(8)" ::: "memory");  // K-step t landed (mine)
        } else {
            asm volatile("s_waitcnt vmcnt(0)" ::: "memory");
        }
        __builtin_amdgcn_s_barrier();  // K-step t landed (all waves)
        const u16* as = lds + (t & 1) * 8192;
        const u16* bs = lds + 16384 + (t & 1) * 8192;
#pragma unroll
        for (int kk = 0; kk < 64; kk += 32) {
            bf16x8 af[4], bf[4];
#pragma unroll
            for (int i = 0; i < 4; ++i) {
                af[i] = ldb(as + (wr * 64 + i * 16 + lr) * 64 + kk + lg * 8);
                bf[i] = ldb(bs + (wc * 64 + i * 16 + lr) * 64 + kk + lg * 8);
            }
#pragma unroll
            for (int mi = 0; mi < 4; ++mi)
#pragma unroll
                for (int ni = 0; ni < 4; ++ni)
                    acc[mi][ni] = MFMA(af[mi], bf[ni], acc[mi][ni]);
        }
        __builtin_amdgcn_s_barrier();  // all waves done reading buf t&1
        if (t + 2 < NT) GSTAGE(t + 2);
    }
#undef GSTAGE

    if (MODE == 0) {  // plain f32 C, N=1024
        float* C = (float*)out0;
#pragma unroll
        for (int mi = 0; mi < 4; ++mi)
#pragma unroll
            for (int ni = 0; ni < 4; ++ni)
#pragma unroll
                for (int r = 0; r < 4; ++r) {
                    long row = m0 + wr * 64 + mi * 16 + lg * 4 + r;
                    long col = n0 + wc * 64 + ni * 16 + lr;
                    C[row * DM + col] = acc[mi][ni][r];
                }
    } else if (n0 < DM) {  // fused RoPE-Q (scaled by 0.125*log2e) -> bf16
        u16* Qb = (u16*)out0;
        const float SC = 0.18033688011112042f;
#pragma unroll
        for (int ni = 0; ni < 4; ++ni) {
            int col = (int)n0 + wc * 64 + ni * 16 + lr;
            int ii = (col & 63) >> 1;
#pragma unroll
            for (int mi = 0; mi < 4; ++mi) {
                long row0 = m0 + wr * 64 + mi * 16 + lg * 4;
#pragma unroll
                for (int r = 0; r < 4; ++r) {
                    int s = (int)(row0 + r) & (SEQ - 1);
                    float2 t = tab[s * 32 + ii];
                    float mine = acc[mi][ni][r];
                    float other = __shfl_xor(mine, 1);
                    float o = ((col & 1) ? (mine * t.x + other * t.y)
                                         : (mine * t.x - other * t.y)) * SC;
                    float oo = __shfl_xor(o, 1);
                    if (!(lr & 1))
                        *(unsigned*)(Qb + (row0 + r) * DM + col) = cvtpk(o, oo);
                }
            }
        }
    } else {  // KV block: cols 0-63 = K (RoPE, unscaled), cols 64-127 = V (transposed)
        u16* Kb = (u16*)out1;
        u16* VbT = (u16*)out2;
        if (wc == 0) {  // K half
#pragma unroll
            for (int ni = 0; ni < 4; ++ni) {
                int col = ni * 16 + lr;  // 0..63
                int ii = col >> 1;
#pragma unroll
                for (int mi = 0; mi < 4; ++mi) {
                    long row0 = m0 + wr * 64 + mi * 16 + lg * 4;
#pragma unroll
                    for (int r = 0; r < 4; ++r) {
                        int s = (int)(row0 + r) & (SEQ - 1);
                        float2 t = tab[s * 32 + ii];
                        float mine = acc[mi][ni][r];
                        float other = __shfl_xor(mine, 1);
                        float o = (col & 1) ? (mine * t.x + other * t.y)
                                            : (mine * t.x - other * t.y);
                        float oo = __shfl_xor(o, 1);
                        if (!(lr & 1))
                            *(unsigned*)(Kb + (row0 + r) * DK + col) = cvtpk(o, oo);
                    }
                }
            }
        } else {  // V half -> VbT[b][d][s]
#pragma unroll
            for (int ni = 0; ni < 4; ++ni) {
                int d = ni * 16 + lr;  // 0..63
#pragma unroll
                for (int mi = 0; mi < 4; ++mi) {
                    long row0 = m0 + wr * 64 + mi * 16 + lg * 4;
#pragma unroll
                    for (int r = 0; r < 4; ++r) {
                        long row = row0 + r;
                        long bb = row >> 11;
                        int s = (int)row & (SEQ - 1);
                        VbT[bb * DK * SEQ + (long)d * SEQ + s] = f2bf(acc[mi][ni][r]);
                    }
                }
            }
        }
    }
}

// ============ attention: 8 waves = 4 q-subs x {even,odd} KV tiles, split-KV merge ============
// LDS: 2 pair-slots x [Ke|Ve|Ko|Vo] 8KB tiles = 64KB. Swizzle: 16B slot ^= (row&7);
// linear LDS dest + inverse-swizzled global source (rule #21).
__device__ __forceinline__ void stage_pair(u16* lds0, int pslot, int kv0,
                                           const u16* Kbase, const u16* Vbase,
                                           int w8, int lane) {
    int row = w8 * 8 + (lane >> 3), slot = lane & 7;
    int sw = (slot ^ (row & 7)) * 8;
    u16* base = lds0 + pslot * 16384 + w8 * 512;
    gload16(Kbase + (long)(kv0 + row) * DK + sw, base);
    gload16(Vbase + (long)row * SEQ + kv0 + sw, base + 4096);
    gload16(Kbase + (long)(kv0 + 64 + row) * DK + sw, base + 8192);
    gload16(Vbase + (long)row * SEQ + kv0 + 64 + sw, base + 12288);
}

__device__ __forceinline__ bf16x8 lds_frag(const u16* tile, int row, int slot) {
    return ldb(tile + row * 64 + ((slot ^ (row & 7)) * 8));
}

// Swapped QK^T: S^T[kv][q] = mfma(K, Q^T); crow(r,hi) = (r&3) + 8*(r>>2) + 4*hi.
// Swapped PV: O^T[d][q] = mfma(V^T, P^T). log2-domain softmax, deferred max (T13).
template <bool MASKED>
__device__ __forceinline__ void attn_tile(int kv0, int q, int lq, int hi,
                                          const u16* Kt, const u16* Vt,
                                          const bf16x8 qf[4],
                                          f32x16& o0, f32x16& o1,
                                          float& m, float& lsum) {
    f32x16 s0 = {}, s1 = {};
    __builtin_amdgcn_s_setprio(1);
#pragma unroll
    for (int ks = 0; ks < 4; ++ks) {
        s0 = MFMA32(lds_frag(Kt, lq, hi + 2 * ks), qf[ks], s0);
        s1 = MFMA32(lds_frag(Kt, lq + 32, hi + 2 * ks), qf[ks], s1);
    }
    __builtin_amdgcn_s_setprio(0);
    if (MASKED) {
#pragma unroll
        for (int r = 0; r < 16; ++r) {
            int crow = (r & 3) + 8 * (r >> 2) + 4 * hi;
            if (kv0 + crow > q) s0[r] = -3e38f;
            if (kv0 + 32 + crow > q) s1[r] = -3e38f;
        }
    }
    float t[8];
#pragma unroll
    for (int j = 0; j < 8; ++j)
        t[j] = fmaxf(fmaxf(s0[j], s0[j + 8]), fmaxf(s1[j], s1[j + 8]));
    float pmax = fmaxf(fmaxf(fmaxf(t[0], t[4]), fmaxf(t[1], t[5])),
                       fmaxf(fmaxf(t[2], t[6]), fmaxf(t[3], t[7])));
    pmax = fmaxf(pmax, __shfl_xor(pmax, 32));
    if (__any(pmax > m + 8.f)) {
        float mnew = fmaxf(m, pmax);
        float fac = fexp2(m - mnew);
        m = mnew;
        lsum *= fac;
        o0 *= fac;
        o1 *= fac;
    }
    float p0[16], p1[16];
#pragma unroll
    for (int r = 0; r < 16; ++r) {
        p0[r] = fexp2(s0[r] - m);
        p1[r] = fexp2(s1[r] - m);
    }
    float su[8];
#pragma unroll
    for (int j = 0; j < 8; ++j)
        su[j] = (p0[j] + p0[j + 8]) + (p1[j] + p1[j + 8]);
    float psum = ((su[0] + su[4]) + (su[1] + su[5])) + ((su[2] + su[6]) + (su[3] + su[7]));
    psum += __shfl_xor(psum, 32);
    lsum += psum;
    bf16x8 pa[4];
#pragma unroll
    for (int g = 0; g < 2; ++g) {
        unsigned a0 = cvtpk(p0[g * 8 + 0], p0[g * 8 + 1]);
        unsigned b0 = cvtpk(p0[g * 8 + 4], p0[g * 8 + 5]);
        swap32(a0, b0);
        unsigned a1 = cvtpk(p0[g * 8 + 2], p0[g * 8 + 3]);
        unsigned b1 = cvtpk(p0[g * 8 + 6], p0[g * 8 + 7]);
        swap32(a1, b1);
        u32x4 u = {a0, a1, b0, b1};
        pa[g] = __builtin_bit_cast(bf16x8, u);
    }
#pragma unroll
    for (int g = 0; g < 2; ++g) {
        unsigned a0 = cvtpk(p1[g * 8 + 0], p1[g * 8 + 1]);
        unsigned b0 = cvtpk(p1[g * 8 + 4], p1[g * 8 + 5]);
        swap32(a0, b0);
        unsigned a1 = cvtpk(p1[g * 8 + 2], p1[g * 8 + 3]);
        unsigned b1 = cvtpk(p1[g * 8 + 6], p1[g * 8 + 7]);
        swap32(a1, b1);
        u32x4 u = {a0, a1, b0, b1};
        pa[2 + g] = __builtin_bit_cast(bf16x8, u);
    }
    __builtin_amdgcn_s_setprio(1);
#pragma unroll
    for (int ks = 0; ks < 4; ++ks) {
        o0 = MFMA32(lds_frag(Vt, lq, hi + 2 * ks), pa[ks], o0);
        o1 = MFMA32(lds_frag(Vt, lq + 32, hi + 2 * ks), pa[ks], o1);
    }
    __builtin_amdgcn_s_setprio(0);
}

// grid: 512 blocks x 512 thr. Waves 0-3: even KV tiles; waves 4-7: odd tiles, same
// 128 q-rows. Per pair p: vmcnt(4) -> barrier -> compute tile 2p+par -> barrier ->
// stage pair p+2 (slots reused only after release barrier). End: split-KV merge.
__global__ __launch_bounds__(512) void k_attn(const u16* __restrict__ Qb,
                                              const u16* __restrict__ Kb,
                                              const u16* __restrict__ VbT,
                                              u16* __restrict__ Ob) {
    __shared__ __align__(16) u16 lds[2][4][4096];  // [pair-slot][Ke|Ve|Ko|Vo] = 64KB
    u16* lds0 = &lds[0][0][0];
    int id = blockIdx.x;
    int h = id & 15, b = (id >> 4) & 1;
    int qslot = id >> 5;                               // 0..15
    int qt = qslot < 8 ? qslot * 2 : 31 - qslot * 2;   // co-resident pair sums const
    int qb0 = qt * 128;
    int tid = threadIdx.x;
    int w8 = tid >> 6, lane = tid & 63;
    int w = w8 & 3, par = w8 >> 2;  // q-sub, even/odd tile parity
    int lq = lane & 31, hi = lane >> 5;
    int q0w = qb0 + 32 * w;
    int q = q0w + lq;
    const u16* Qp = Qb + (long)(b * SEQ + q) * DM + h * DK + hi * 8;
    bf16x8 qf[4];
#pragma unroll
    for (int ks = 0; ks < 4; ++ks) qf[ks] = ldb(Qp + ks * 16);
    const u16* Kbase = Kb + (long)b * SEQ * DK;
    const u16* Vbase = VbT + (long)b * DK * SEQ;
    f32x16 o0 = {}, o1 = {};
    float m = -1e30f, lsum = 0.f;

    int npair = qt + 1;  // nt = 2*qt+2 tiles = qt+1 pairs of 64-kv tiles
    stage_pair(lds0, 0, 0, Kbase, Vbase, w8, lane);
    if (npair > 1) stage_pair(lds0, 1, 128, Kbase, Vbase, w8, lane);
    for (int p = 0; p < npair; ++p) {
        if (p + 1 < npair) {
            asm volatile("s_waitcnt vmcnt(4)" ::: "memory");  // pair p landed (mine)
        } else {
            asm volatile("s_waitcnt vmcnt(0)" ::: "memory");
        }
        __builtin_amdgcn_s_barrier();  // pair p landed (all waves)
        int t = 2 * p + par;
        int kv0 = t * 64;
        const u16* Kt = lds0 + (p & 1) * 16384 + par * 8192;
        const u16* Vt = Kt + 4096;
        if (kv0 <= q0w + 31) {
            if (kv0 + 63 <= q0w)
                attn_tile<false>(kv0, q, lq, hi, Kt, Vt, qf, o0, o1, m, lsum);
            else
                attn_tile<true>(kv0, q, lq, hi, Kt, Vt, qf, o0, o1, m, lsum);
        }
        __builtin_amdgcn_s_barrier();  // all waves done reading pair p's slots
        if (p + 2 < npair)
            stage_pair(lds0, p & 1, (2 * p + 4) * 64, Kbase, Vbase, w8, lane);
    }

    // ---- split-KV merge: odd waves publish (O, m, l); even waves combine ----
    __syncthreads();
    float* mrg = (float*)lds0;  // floats [0, 8704) = 34KB; Ot region starts at u16 20480
    if (par == 1) {
        float* dst = mrg + (w * 64 + lane) * 34;
#pragma unroll
        for (int r = 0; r < 16; ++r) { dst[r] = o0[r]; dst[16 + r] = o1[r]; }
        dst[32] = m;
        dst[33] = lsum;
    }
    __syncthreads();
    if (par == 0) {
        const float* src = mrg + (w * 64 + lane) * 34;
        float m_o = src[32], l_o = src[33];
        float mstar = fmaxf(m, m_o);
        float fe = fexp2(m - mstar), fo = fexp2(m_o - mstar);
        float linv = 1.f / (lsum * fe + l_o * fo);
#pragma unroll
        for (int r = 0; r < 16; ++r) {
            o0[r] = (o0[r] * fe + src[r] * fo) * linv;
            o1[r] = (o1[r] * fe + src[16 + r] * fo) * linv;
        }
        u16* Ot = lds0 + 20480 + w * 2304;  // 32 x 72 u16 per wave (disjoint from mrg)
#pragma unroll
        for (int rq = 0; rq < 4; ++rq) {
            uint2 u0, u1;
            u0.x = cvtpk(o0[4 * rq + 0], o0[4 * rq + 1]);
            u0.y = cvtpk(o0[4 * rq + 2], o0[4 * rq + 3]);
            u1.x = cvtpk(o1[4 * rq + 0], o1[4 * rq + 1]);
            u1.y = cvtpk(o1[4 * rq + 2], o1[4 * rq + 3]);
            *(uint2*)&Ot[lq * 72 + rq * 8 + hi * 4] = u0;
            *(uint2*)&Ot[lq * 72 + 32 + rq * 8 + hi * 4] = u1;
        }
#pragma unroll
        for (int i2 = 0; i2 < 4; ++i2) {
            int c = i2 * 64 + lane;
            int row = c >> 3, col = (c & 7) * 8;
            u16x8 v = *(const u16x8*)&Ot[row * 72 + col];
            *(u16x8*)(Ob + (long)(b * SEQ + q0w + row) * DM + h * DK + col) = v;
        }
    }
}

extern "C" void kernel_launch(void* const* d_in, const int* in_sizes, int n_in,
                              void* d_out, int out_size, void* d_ws, size_t ws_size,
                              hipStream_t stream) {
    const float* x = (const float*)d_in[0];
    const float* Wq = (const float*)d_in[1];
    const float* Wk = (const float*)d_in[2];
    const float* Wv = (const float*)d_in[3];
    const float* Wo = (const float*)d_in[4];
    float* out = (float*)d_out;

    const int M = 2 * SEQ;  // 4096 rows
    char* p = (char*)d_ws;
    u16* xb = (u16*)p;        p += (size_t)M * DM * 2;          // 8 MB
    u16* WqkvT = (u16*)p;     p += (size_t)(DM + 2 * DK) * DM * 2;  // 2.25 MB
    u16* WobT = (u16*)p;      p += (size_t)DM * DM * 2;         // 2 MB
    u16* Qb = (u16*)p;        p += (size_t)M * DM * 2;          // 8 MB
    u16* Kb = (u16*)p;        p += (size_t)M * DK * 2;          // 512 KB
    u16* VbT = (u16*)p;       p += (size_t)M * DK * 2;          // 512 KB
    u16* Ob = (u16*)p;        p += (size_t)M * DM * 2;          // 8 MB
    float2* tab = (float2*)p; p += (size_t)SEQ * 32 * 8;        // 512 KB

    const size_t GEMM_LDS = 2 * 2 * 8192 * sizeof(u16);  // 64 KB -> 2 blocks/CU

    // 1) fused prep: cvt + trig + weight transposes (one launch)
    k_prep<<<NB_CVT + NB_TRIG + NB_TQ + NB_TK + NB_TV + NB_TO, 256, 0, stream>>>(
        x, xb, tab, Wq, Wk, Wv, WqkvT, Wo, WobT);

    // 2) fused QKV projection: N=1152; epi = RoPE-Q -> Qb, RoPE-K -> Kb, V^T -> VbT
    k_gemm_r2<1><<<dim3((DM + 2 * DK) / 128, M / 128), 256, GEMM_LDS, stream>>>(
        xb, WqkvT, Qb, Kb, VbT, tab);

    // 3) attention (8-wave split-KV blocks, ring-2-pairs, counted vmcnt)
    k_attn<<<dim3(2 * NH * (SEQ / 128)), 512, 0, stream>>>(Qb, Kb, VbT, Ob);

    // 4) output projection -> d_out
    k_gemm_r2<0><<<dim3(DM / 128, M / 128), 256, GEMM_LDS, stream>>>(
        Ob, WobT, out, nullptr, nullptr, nullptr);
}